// Round 20
// baseline (525.987 us; speedup 1.0000x reference)
//
#include <hip/hip_runtime.h>
#include <math.h>

#define TPB 256

constexpr int BN_  = 2;
constexpr int CDIM = 128;
constexpr int HH   = 192;
constexpr int WW   = 192;
constexpr int HWc  = HH * WW;      // 36864
constexpr int C3   = 384;
constexpr int HID  = 340;
constexpr int NL2  = 288;          // split-L chunks for QK^T
constexpr int CH2  = HWc / NL2;    // 128
constexpr int CV   = 288;          // split-L chunks for cov (128 cols each)

typedef unsigned short bf16_t;
typedef __attribute__((ext_vector_type(8))) __bf16 bf16x8;
typedef __attribute__((ext_vector_type(4))) float f32x4;

__device__ __forceinline__ float b2f(bf16_t v) {
  unsigned u = ((unsigned)v) << 16;
  return __uint_as_float(u);
}
__device__ __forceinline__ bf16_t f2b(float f) {
  unsigned u = __float_as_uint(f);
  unsigned r = (u + 0x7FFFu + ((u >> 16) & 1u)) >> 16;
  return (bf16_t)r;
}
__device__ __forceinline__ float ldf(const float* p) { return *p; }
__device__ __forceinline__ float ldf(const bf16_t* p) { return b2f(*p); }
__device__ __forceinline__ void stf(float* p, float v) { *p = v; }
__device__ __forceinline__ void stf(bf16_t* p, float v) { *p = f2b(v); }

__device__ __forceinline__ void ldv4(const float* p, float* v) {
  float4 t = *(const float4*)p;
  v[0] = t.x; v[1] = t.y; v[2] = t.z; v[3] = t.w;
}
__device__ __forceinline__ void ldv4(const bf16_t* p, float* v) {
  ushort4 t = *(const ushort4*)p;
  v[0] = b2f(t.x); v[1] = b2f(t.y); v[2] = b2f(t.z); v[3] = b2f(t.w);
}
__device__ __forceinline__ void stv4(float* p, const float* v) {
  float4 t; t.x = v[0]; t.y = v[1]; t.z = v[2]; t.w = v[3];
  *(float4*)p = t;
}
__device__ __forceinline__ void stv4(bf16_t* p, const float* v) {
  ushort4 t; t.x = f2b(v[0]); t.y = f2b(v[1]); t.z = f2b(v[2]); t.w = f2b(v[3]);
  *(ushort4*)p = t;
}

__device__ __forceinline__ float gelu_f(float x) {
  return 0.5f * x * (1.0f + erff(x * 0.7071067811865475f));
}

__device__ __forceinline__ void unpack8(uint4 v, float* rv) {
  unsigned wv[4] = {v.x, v.y, v.z, v.w};
#pragma unroll
  for (int j = 0; j < 8; ++j)
    rv[j + 1] = b2f((bf16_t)((wv[j >> 1] >> ((j & 1) * 16)) & 0xFFFFu));
}
__device__ __forceinline__ uint4 pack8(const float* a) {
  uint4 o;
  unsigned w[4];
#pragma unroll
  for (int p = 0; p < 4; ++p) {
    unsigned lo = f2b(a[2 * p]), hi = f2b(a[2 * p + 1]);
    w[p] = lo | (hi << 16);
  }
  o.x = w[0]; o.y = w[1]; o.z = w[2]; o.w = w[3];
  return o;
}
__device__ __forceinline__ float sumsq8(uint4 v) {
  unsigned w[4] = {v.x, v.y, v.z, v.w};
  float s = 0.f;
#pragma unroll
  for (int j = 0; j < 8; ++j) {
    float t = b2f((bf16_t)((w[j >> 1] >> ((j & 1) * 16)) & 0xFFFFu));
    s += t * t;
  }
  return s;
}

// load a 10-wide window (8-aligned interior + 2 edges) for depthwise rows
__device__ __forceinline__ void dwrow(const bf16_t* rp, int w8, float* rv) {
  unpack8(*(const uint4*)rp, rv);
  rv[0] = (w8 > 0) ? b2f(rp[-1]) : 0.f;
  rv[9] = (w8 + 8 < WW) ? b2f(rp[8]) : 0.f;
}

// group tables
__device__ __constant__ int dGSZ[4]   = {16, 32, 32, 48};
__device__ __constant__ int dGST[4]   = {0, 16, 48, 80};
__device__ __constant__ int dAOFF[4]  = {0, 256, 1280, 2304};   // attraw/attS slots
__device__ __constant__ int dABASE[4] = {0, 512, 2560, 4608};   // attF (b-interleaved)

// ---------------- workspace layout (byte offsets) ----------------
constexpr size_t oATTS2   = 65536;
constexpr size_t oWB      = 131072;            // bf16 weight arena (468,992 B)
constexpr size_t oQKP2    = 602112;            // qk 2-stage partials (294,912 B)
constexpr size_t oMUPC    = 897024;            // cov mu partials 288*128 fp32 (147,456 B)
constexpr size_t oATTS    = 1327104;           // attF
constexpr size_t oNORMQ   = 1363968;           // stores 1/norm (by channel)
constexpr size_t oNORMK   = 1364992;           // stores 1/norm (by channel)
constexpr size_t oIDX     = 1366016;
constexpr size_t oMU      = 1366528;
constexpr size_t oCOV     = 1367040;
constexpr size_t oQKV     = 1572864;           // 56,623,104 B
constexpr size_t oXN      = 58195968;          // 18,874,368 B  xn / qk-partials / x1b
constexpr size_t oOUTALL  = 77070336;          // 18,874,368 B
constexpr size_t oSBUF    = 95944704;          // 18,874,368 B
constexpr size_t WS_NEED  = 114819072;
// aliases:
constexpr size_t oCHUNK1  = oOUTALL;
constexpr size_t oCOVPART = oOUTALL;
constexpr size_t oCOVP2   = oSBUF;
constexpr size_t oQKPART  = oXN;
constexpr size_t oY0C     = oOUTALL;           // FFN y0c chunk (<=33.6 MB, fits 37.7 MB span)
constexpr size_t oZ       = oQKV;              // FFN z (50.1 MB, fits 56.6 MB span)
constexpr size_t oX1B     = oXN;

// bf16 weight arena element offsets
constexpr int eWQ   = 0;
constexpr int eGATE = 49152;
constexpr int eDOWN = 65536;
constexpr int eUP   = 73728;
constexpr int ePROJ = 81920;
constexpr int eFFI  = 98304;
constexpr int eFFO  = 185344;
constexpr int eTOT  = 234496;

// ---------------- weight fp32->bf16 pre-conversion ----------------
__global__ __launch_bounds__(TPB) void k_wcvt(const float* __restrict__ wq,
                                              const float* __restrict__ gate,
                                              const float* __restrict__ down,
                                              const float* __restrict__ up,
                                              const float* __restrict__ proj,
                                              const float* __restrict__ ffi,
                                              const float* __restrict__ ffo,
                                              bf16_t* __restrict__ wb) {
  int t = blockIdx.x * TPB + threadIdx.x;
  if (t >= eTOT) return;
  int u = t;
  if (u < 49152) { wb[eWQ + u] = f2b(wq[u]); return; }
  u -= 49152;
  if (u < 16384) { wb[eGATE + u] = f2b(gate[u]); return; }
  u -= 16384;
  if (u < 8192)  { wb[eDOWN + u] = f2b(down[u]); return; }
  u -= 8192;
  if (u < 8192)  { wb[eUP + u] = f2b(up[u]); return; }
  u -= 8192;
  if (u < 16384) { wb[ePROJ + u] = f2b(proj[u]); return; }
  u -= 16384;
  if (u < 87040) { wb[eFFI + u] = f2b(ffi[u]); return; }
  u -= 87040;
  {
    int o = u / 384, k = u - o * 384;
    wb[eFFO + u] = (k < HID) ? f2b(ffo[o * HID + k]) : (bf16_t)0;
  }
}

// ---------------- LayerNorm over channel dim (templated input) ----------------
template <typename TI>
__global__ __launch_bounds__(TPB) void k_ln(const TI* __restrict__ x,
                                            const float* __restrict__ w,
                                            const float* __restrict__ bias,
                                            bf16_t* __restrict__ out) {
  int t = blockIdx.x * TPB + threadIdx.x;
  if (t >= BN_ * HWc) return;
  int b = t / HWc, l = t - b * HWc;
  const TI* xb = x + (size_t)b * CDIM * HWc + l;
  float s = 0.f, s2 = 0.f;
#pragma unroll 4
  for (int c = 0; c < CDIM; ++c) { float v = ldf(&xb[(size_t)c * HWc]); s += v; s2 += v * v; }
  float mu  = s * (1.f / CDIM);
  float var = s2 * (1.f / CDIM) - mu * mu;
  float inv = 1.f / sqrtf(var + 1e-5f);
  bf16_t* ob = out + (size_t)b * CDIM * HWc + l;
#pragma unroll 4
  for (int c = 0; c < CDIM; ++c)
    stf(&ob[(size_t)c * HWc], (ldf(&xb[(size_t)c * HWc]) - mu) * inv * w[c] + bias[c]);
}

// ============ MFMA channel GEMM, ACT-RESIDENT (K = KT <= 128), 128-l tile ============
// EPI: 0 = (+bias), 1 = (+bias)+aux, 2 = gelu(+bias)*aux, 3 = gelu(+bias)*At (aux==in)
template <typename TO, typename TA, int KT, int EPI>
__global__ __launch_bounds__(TPB) void k_mgA(const bf16_t* __restrict__ W,
                                             const bf16_t* __restrict__ W2, int osplit,
                                             const float* __restrict__ bias,
                                             const bf16_t* __restrict__ in,
                                             const TA* __restrict__ aux,
                                             TO* __restrict__ out, int O,
                                             int ibr, int obr, int abr) {
  constexpr int L  = HWc;
  constexpr int PK = KT + 8;
  constexpr int KH = KT / 2;
  constexpr int SH = (KT == 128) ? 6 : 5;
  __shared__ bf16_t At[128 * PK];
  __shared__ bf16_t Wt[64 * PK];
  int b = blockIdx.y;
  const bf16_t* inb  = in  + (size_t)b * ibr * L;
  const TA*     auxb = aux ? aux + (size_t)b * abr * L : nullptr;
  TO*           outb = out + (size_t)b * obr * L;
  int l0 = blockIdx.x * 128;
  int tid = threadIdx.x, lane = tid & 63, wid = tid >> 6;
  int wm = wid >> 1, wn = wid & 1;
  int cl = lane & 15, rg = lane >> 4;

#pragma unroll
  for (int r = 0; r < (KH * 16) / TPB; ++r) {
    int u  = tid + r * TPB;
    int k2 = u & (KH - 1), lb = u >> SH;
    int ka = k2 * 2;
    uint4 rowA = *(const uint4*)(&inb[(size_t)ka * L + l0 + lb * 8]);
    uint4 rowB = *(const uint4*)(&inb[(size_t)(ka + 1) * L + l0 + lb * 8]);
    unsigned wa[4] = {rowA.x, rowA.y, rowA.z, rowA.w};
    unsigned wb[4] = {rowB.x, rowB.y, rowB.z, rowB.w};
#pragma unroll
    for (int j = 0; j < 8; ++j) {
      unsigned va = (wa[j >> 1] >> ((j & 1) * 16)) & 0xFFFFu;
      unsigned vb = (wb[j >> 1] >> ((j & 1) * 16)) & 0xFFFFu;
      *(unsigned*)(&At[(lb * 8 + j) * PK + ka]) = va | (vb << 16);
    }
  }

  int noc = (O + 63) >> 6;
  for (int oc = 0; oc < noc; ++oc) {
    int o0 = oc * 64;
#pragma unroll
    for (int r = 0; r < (64 * KT / 8) / TPB; ++r) {
      int e = tid + r * TPB;
      int o = e / (KT / 8), k8 = (e % (KT / 8)) * 8;
      int og = o0 + o;
      uint4 wv = {0u, 0u, 0u, 0u};
      if (og < O) {
        const bf16_t* wrow = (og < osplit) ? (W + (size_t)og * KT)
                                           : (W2 + (size_t)(og - osplit) * KT);
        wv = *(const uint4*)(&wrow[k8]);
      }
      *(uint4*)(&Wt[o * PK + k8]) = wv;
    }
    __syncthreads();
    f32x4 acc[2][4];
#pragma unroll
    for (int m = 0; m < 2; ++m)
#pragma unroll
      for (int n = 0; n < 4; ++n) acc[m][n] = (f32x4){0.f, 0.f, 0.f, 0.f};
#pragma unroll
    for (int kk = 0; kk < KT / 32; ++kk) {
      int kof = kk * 32 + rg * 8;
      bf16x8 a[2], bfr[4];
#pragma unroll
      for (int m = 0; m < 2; ++m)
        a[m] = *(const bf16x8*)(&Wt[(wm * 32 + m * 16 + cl) * PK + kof]);
#pragma unroll
      for (int n = 0; n < 4; ++n)
        bfr[n] = *(const bf16x8*)(&At[(wn * 64 + n * 16 + cl) * PK + kof]);
#pragma unroll
      for (int m = 0; m < 2; ++m)
#pragma unroll
        for (int n = 0; n < 4; ++n)
          acc[m][n] = __builtin_amdgcn_mfma_f32_16x16x32_bf16(bfr[n], a[m], acc[m][n], 0, 0, 0);
    }
    __syncthreads();
#pragma unroll
    for (int m = 0; m < 2; ++m) {
      int og = o0 + wm * 32 + m * 16 + cl;
      if (og >= O) continue;
      float bv = bias ? bias[og] : 0.f;
#pragma unroll
      for (int n = 0; n < 4; ++n) {
        int lcol = l0 + wn * 64 + n * 16 + rg * 4;
        size_t off = (size_t)og * L + lcol;
        float v[4];
#pragma unroll
        for (int r = 0; r < 4; ++r) v[r] = acc[m][n][r] + bv;
        if (EPI == 1) {
          float a4[4]; ldv4(&auxb[off], a4);
#pragma unroll
          for (int r = 0; r < 4; ++r) v[r] += a4[r];
        } else if (EPI == 2) {
          float a4[4]; ldv4(&auxb[off], a4);
#pragma unroll
          for (int r = 0; r < 4; ++r) v[r] = gelu_f(v[r]) * a4[r];
        } else if (EPI == 3) {
          int lloc = wn * 64 + n * 16 + rg * 4;
#pragma unroll
          for (int r = 0; r < 4; ++r)
            v[r] = gelu_f(v[r]) * b2f(At[(lloc + r) * PK + og]);
        }
        stv4(&outb[off], v);
      }
    }
  }
}

// ============ MFMA channel GEMM, K-LOOP, O=128 in regs, 128-l tile ============
template <typename TO, typename TA, int EPI>
__global__ __launch_bounds__(TPB) void k_mgB(const bf16_t* __restrict__ Wb,
                                             const float* __restrict__ bias,
                                             const bf16_t* __restrict__ in,
                                             const TA* __restrict__ aux,
                                             TO* __restrict__ out, int O, int K,
                                             int ibr, int obr, int abr) {
  constexpr int L = HWc;
  constexpr int PK = 72, BK = 64, WSTR = 384;
  __shared__ bf16_t At[128 * PK];
  __shared__ bf16_t Wt[128 * PK];
  int b = blockIdx.y;
  const bf16_t* inb  = in  + (size_t)b * ibr * L;
  const TA*     auxb = aux ? aux + (size_t)b * abr * L : nullptr;
  TO*           outb = out + (size_t)b * obr * L;
  int l0 = blockIdx.x * 128;
  int tid = threadIdx.x, lane = tid & 63, wid = tid >> 6;
  int wm = wid >> 1, wn = wid & 1;
  int cl = lane & 15, rg = lane >> 4;

  f32x4 acc[4][4];
#pragma unroll
  for (int m = 0; m < 4; ++m)
#pragma unroll
    for (int n = 0; n < 4; ++n) acc[m][n] = (f32x4){0.f, 0.f, 0.f, 0.f};

  for (int k0 = 0; k0 < K; k0 += BK) {
#pragma unroll
    for (int r = 0; r < 2; ++r) {
      int u = tid + r * TPB;
      int k2 = u & 31, lb = u >> 5;
      int ka = k0 + k2 * 2;
      uint4 rowA = {0u,0u,0u,0u}, rowB = {0u,0u,0u,0u};
      if (ka < K)     rowA = *(const uint4*)(&inb[(size_t)ka * L + l0 + lb * 8]);
      if (ka + 1 < K) rowB = *(const uint4*)(&inb[(size_t)(ka + 1) * L + l0 + lb * 8]);
      unsigned wa[4] = {rowA.x, rowA.y, rowA.z, rowA.w};
      unsigned wb[4] = {rowB.x, rowB.y, rowB.z, rowB.w};
#pragma unroll
      for (int j = 0; j < 8; ++j) {
        unsigned va = (wa[j >> 1] >> ((j & 1) * 16)) & 0xFFFFu;
        unsigned vb = (wb[j >> 1] >> ((j & 1) * 16)) & 0xFFFFu;
        *(unsigned*)(&At[(lb * 8 + j) * PK + k2 * 2]) = va | (vb << 16);
      }
    }
#pragma unroll
    for (int r = 0; r < 4; ++r) {
      int e = tid + r * TPB;
      int o = e >> 3, k8 = (e & 7) * 8;
      uint4 wv = *(const uint4*)(&Wb[(size_t)o * WSTR + k0 + k8]);
      *(uint4*)(&Wt[o * PK + k8]) = wv;
    }
    __syncthreads();
#pragma unroll
    for (int kk = 0; kk < 2; ++kk) {
      int kof = kk * 32 + rg * 8;
      bf16x8 a[4], bfr[4];
#pragma unroll
      for (int m = 0; m < 4; ++m)
        a[m] = *(const bf16x8*)(&Wt[(wm * 64 + m * 16 + cl) * PK + kof]);
#pragma unroll
      for (int n = 0; n < 4; ++n)
        bfr[n] = *(const bf16x8*)(&At[(wn * 64 + n * 16 + cl) * PK + kof]);
#pragma unroll
      for (int m = 0; m < 4; ++m)
#pragma unroll
        for (int n = 0; n < 4; ++n)
          acc[m][n] = __builtin_amdgcn_mfma_f32_16x16x32_bf16(bfr[n], a[m], acc[m][n], 0, 0, 0);
    }
    __syncthreads();
  }
#pragma unroll
  for (int m = 0; m < 4; ++m) {
    int og = wm * 64 + m * 16 + cl;
    if (og >= O) continue;
    float bv = bias ? bias[og] : 0.f;
#pragma unroll
    for (int n = 0; n < 4; ++n) {
      int lcol = l0 + wn * 64 + n * 16 + rg * 4;
      size_t off = (size_t)og * L + lcol;
      float v[4];
#pragma unroll
      for (int r = 0; r < 4; ++r) v[r] = acc[m][n][r] + bv;
      if (EPI == 1) {
        float a4[4]; ldv4(&auxb[off], a4);
#pragma unroll
        for (int r = 0; r < 4; ++r) v[r] += a4[r];
      } else if (EPI == 2) {
        float a4[4]; ldv4(&auxb[off], a4);
#pragma unroll
        for (int r = 0; r < 4; ++r) v[r] = gelu_f(v[r]) * a4[r];
      }
      stv4(&outb[off], v);
    }
  }
}

// ============ fused gate->down->up->proj chain (4 GEMMs, LDS-resident) ============
template <int KT>
__device__ __forceinline__ void stage_w64(bf16_t* Wt, const bf16_t* Wsrc, int tid) {
  constexpr int PKl = KT + 8;
#pragma unroll
  for (int r = 0; r < (64 * KT / 8) / TPB; ++r) {
    int e = tid + r * TPB;
    int o = e / (KT / 8), k8 = (e % (KT / 8)) * 8;
    *(uint4*)(&Wt[o * PKl + k8]) = *(const uint4*)(&Wsrc[(size_t)o * KT + k8]);
  }
}

template <int KT>
__device__ __forceinline__ void gemm_tile(const bf16_t* Wt, const bf16_t* Ain,
                                          int wm, int wn, int cl, int rg,
                                          f32x4 acc[2][4]) {
  constexpr int PKl = KT + 8;
#pragma unroll
  for (int m = 0; m < 2; ++m)
#pragma unroll
    for (int n = 0; n < 4; ++n) acc[m][n] = (f32x4){0.f, 0.f, 0.f, 0.f};
#pragma unroll
  for (int kk = 0; kk < KT / 32; ++kk) {
    int kof = kk * 32 + rg * 8;
    bf16x8 a[2], bb[4];
#pragma unroll
    for (int m = 0; m < 2; ++m)
      a[m] = *(const bf16x8*)(&Wt[(wm * 32 + m * 16 + cl) * PKl + kof]);
#pragma unroll
    for (int n = 0; n < 4; ++n)
      bb[n] = *(const bf16x8*)(&Ain[(wn * 64 + n * 16 + cl) * PKl + kof]);
#pragma unroll
    for (int m = 0; m < 2; ++m)
#pragma unroll
      for (int n = 0; n < 4; ++n)
        acc[m][n] = __builtin_amdgcn_mfma_f32_16x16x32_bf16(bb[n], a[m], acc[m][n], 0, 0, 0);
  }
}

__global__ __launch_bounds__(TPB) void k_mlp4(const bf16_t* __restrict__ wbarena,
                                              const float* __restrict__ gb,
                                              const float* __restrict__ db,
                                              const float* __restrict__ ub,
                                              const bf16_t* __restrict__ sbuf,
                                              const bf16_t* __restrict__ out_all,
                                              const float* __restrict__ x,
                                              bf16_t* __restrict__ x1b) {
  constexpr int L = HWc;
  constexpr int PK = 136;   // K=128 buffers
  constexpr int PK3 = 72;   // K=64 buffer
  extern __shared__ char sm[];
  bf16_t* As = (bf16_t*)sm;                       // [128][PK] input s; reused as Ao
  bf16_t* Ag = (bf16_t*)(sm + 34816);             // [128][PK] gated
  bf16_t* Ad = (bf16_t*)(sm + 69632);             // [128][PK3] dbuf
  bf16_t* Wt = (bf16_t*)(sm + 88064);             // [64][PK]
  bf16_t* Ao = As;
  int b = blockIdx.y;
  int l0 = blockIdx.x * 128;
  int tid = threadIdx.x, lane = tid & 63, wid = tid >> 6;
  int wm = wid >> 1, wn = wid & 1;
  int cl = lane & 15, rg = lane >> 4;
  const bf16_t* inb = sbuf + (size_t)b * CDIM * L;

  // stage As = s tile (packed pairs, same layout as k_mgA At)
#pragma unroll
  for (int r = 0; r < 4; ++r) {
    int u = tid + r * TPB;
    int k2 = u & 63, lb = u >> 6;
    int ka = k2 * 2;
    uint4 rowA = *(const uint4*)(&inb[(size_t)ka * L + l0 + lb * 8]);
    uint4 rowB = *(const uint4*)(&inb[(size_t)(ka + 1) * L + l0 + lb * 8]);
    unsigned wa[4] = {rowA.x, rowA.y, rowA.z, rowA.w};
    unsigned wbv[4] = {rowB.x, rowB.y, rowB.z, rowB.w};
#pragma unroll
    for (int j = 0; j < 8; ++j) {
      unsigned va = (wa[j >> 1] >> ((j & 1) * 16)) & 0xFFFFu;
      unsigned vb = (wbv[j >> 1] >> ((j & 1) * 16)) & 0xFFFFu;
      *(unsigned*)(&As[(lb * 8 + j) * PK + ka]) = va | (vb << 16);
    }
  }

  // GEMM1: gated = gelu(Wg*s + gb) * s  -> Ag
  for (int oc = 0; oc < 2; ++oc) {
    stage_w64<128>(Wt, wbarena + eGATE + (size_t)(oc * 64) * 128, tid);
    __syncthreads();
    f32x4 acc[2][4];
    gemm_tile<128>(Wt, As, wm, wn, cl, rg, acc);
    __syncthreads();
#pragma unroll
    for (int m = 0; m < 2; ++m) {
      int og = oc * 64 + wm * 32 + m * 16 + cl;
      float bv = gb[og];
#pragma unroll
      for (int n = 0; n < 4; ++n) {
        int lloc = wn * 64 + n * 16 + rg * 4;
#pragma unroll
        for (int r = 0; r < 4; ++r) {
          float v = gelu_f(acc[m][n][r] + bv) * b2f(As[(lloc + r) * PK + og]);
          Ag[(lloc + r) * PK + og] = f2b(v);
        }
      }
    }
    __syncthreads();
  }

  // GEMM2: dbuf = Wd*gated + db  -> Ad   (O=64)
  stage_w64<128>(Wt, wbarena + eDOWN, tid);
  __syncthreads();
  {
    f32x4 acc[2][4];
    gemm_tile<128>(Wt, Ag, wm, wn, cl, rg, acc);
    __syncthreads();
#pragma unroll
    for (int m = 0; m < 2; ++m) {
      int og = wm * 32 + m * 16 + cl;        // 0..63
      float bv = db[og];
#pragma unroll
      for (int n = 0; n < 4; ++n) {
        int lloc = wn * 64 + n * 16 + rg * 4;
#pragma unroll
        for (int r = 0; r < 4; ++r)
          Ad[(lloc + r) * PK3 + og] = f2b(acc[m][n][r] + bv);
      }
    }
    __syncthreads();
  }

  // GEMM3: out_all_new = Wu*dbuf + ub + out_all  -> Ao (=As, bf16)
  const bf16_t* oab = out_all + (size_t)b * CDIM * L;
  for (int oc = 0; oc < 2; ++oc) {
    stage_w64<64>(Wt, wbarena + eUP + (size_t)(oc * 64) * 64, tid);
    __syncthreads();
    f32x4 acc[2][4];
    gemm_tile<64>((const bf16_t*)Wt, Ad, wm, wn, cl, rg, acc);
    __syncthreads();
#pragma unroll
    for (int m = 0; m < 2; ++m) {
      int og = oc * 64 + wm * 32 + m * 16 + cl;
      float bv = ub[og];
#pragma unroll
      for (int n = 0; n < 4; ++n) {
        int lloc = wn * 64 + n * 16 + rg * 4;
        float a4[4]; ldv4(&oab[(size_t)og * L + l0 + lloc], a4);
#pragma unroll
        for (int r = 0; r < 4; ++r)
          Ao[(lloc + r) * PK + og] = f2b(acc[m][n][r] + bv + a4[r]);
      }
    }
    __syncthreads();
  }

  // GEMM4: x1b = x + Wp*out_all_new
  const float* xb = x + (size_t)b * CDIM * L;
  bf16_t* x1bb = x1b + (size_t)b * CDIM * L;
  for (int oc = 0; oc < 2; ++oc) {
    stage_w64<128>(Wt, wbarena + ePROJ + (size_t)(oc * 64) * 128, tid);
    __syncthreads();
    f32x4 acc[2][4];
    gemm_tile<128>(Wt, Ao, wm, wn, cl, rg, acc);
    __syncthreads();
#pragma unroll
    for (int m = 0; m < 2; ++m) {
      int og = oc * 64 + wm * 32 + m * 16 + cl;
#pragma unroll
      for (int n = 0; n < 4; ++n) {
        int lcol = l0 + wn * 64 + n * 16 + rg * 4;
        size_t off = (size_t)og * L + lcol;
        float v[4], a4[4];
        ldv4(&xb[off], a4);
#pragma unroll
        for (int r = 0; r < 4; ++r) v[r] = acc[m][n][r] + a4[r];
        stv4(&x1bb[off], v);
      }
    }
  }
}

// ---------------- depthwise 3x3 SAME, 2 rows x 8 px per thread ----------------
__global__ __launch_bounds__(TPB) void k_dw3v(const bf16_t* __restrict__ in,
                                              const float* __restrict__ wt,
                                              bf16_t* __restrict__ out,
                                              int Cc, int c0, int CoutTotal, long totalG) {
  long t = (long)blockIdx.x * TPB + threadIdx.x;
  if (t >= totalG) return;
  int g = (int)(t % (HWc / 16));
  long bc = t / (HWc / 16);
  int cl = (int)(bc % Cc);
  int b = (int)(bc / Cc);
  int rp = g / (WW / 8), w8 = (g % (WW / 8)) * 8;
  int h = rp * 2;
  const bf16_t* ib = in + ((size_t)b * Cc + cl) * HWc;
  const float* wc = wt + (size_t)(c0 + cl) * 9;
  float rv[4][10];
#pragma unroll
  for (int dy = 0; dy < 4; ++dy) {
    int hh = h - 1 + dy;
    if (hh < 0 || hh >= HH) {
#pragma unroll
      for (int j = 0; j < 10; ++j) rv[dy][j] = 0.f;
    } else {
      dwrow(ib + hh * WW + w8, w8, rv[dy]);
    }
  }
  float a0[8], a1[8];
#pragma unroll
  for (int j = 0; j < 8; ++j) {
    float s0 = 0.f, s1 = 0.f;
#pragma unroll
    for (int dy = 0; dy < 3; ++dy)
#pragma unroll
      for (int dx = 0; dx < 3; ++dx) {
        float wv = wc[dy * 3 + dx];
        s0 += rv[dy][j + dx] * wv;
        s1 += rv[dy + 1][j + dx] * wv;
      }
    a0[j] = s0; a1[j] = s1;
  }
  bf16_t* ob = out + ((size_t)b * CoutTotal + c0 + cl) * HWc + h * WW + w8;
  *(uint4*)ob = pack8(a0);
  *(uint4*)(ob + WW) = pack8(a1);
}

// ---------------- MFMA cov partials + per-channel mu partials ----------------
__global__ __launch_bounds__(TPB) void k_cov4(const bf16_t* __restrict__ qkv,
                                              float* __restrict__ part,
                                              float* __restrict__ mupartC) {
  constexpr int PK = 136;
  __shared__ bf16_t Xt[128 * PK];
  int chunk = blockIdx.x;
  int base = chunk * 128;
  int tid = threadIdx.x, lane = tid & 63, wid = tid >> 6;
  int wm = wid >> 1, wn = wid & 1;
  int cl = lane & 15, rg = lane >> 4;
#pragma unroll
  for (int r = 0; r < 8; ++r) {
    int u = tid + r * TPB;
    int c = u >> 4, l8 = (u & 15) * 8;
    uint4 v0 = *(const uint4*)(&qkv[(size_t)c * HWc + base + l8]);
    uint4 v1 = *(const uint4*)(&qkv[(size_t)C3 * HWc + (size_t)c * HWc + base + l8]);
    unsigned w0[4] = {v0.x, v0.y, v0.z, v0.w};
    unsigned w1[4] = {v1.x, v1.y, v1.z, v1.w};
    float cf[8];
#pragma unroll
    for (int j = 0; j < 8; ++j) {
      float a = b2f((bf16_t)((w0[j >> 1] >> ((j & 1) * 16)) & 0xFFFFu));
      float bq = b2f((bf16_t)((w1[j >> 1] >> ((j & 1) * 16)) & 0xFFFFu));
      cf[j] = 0.5f * (a + bq);
    }
    *(uint4*)(&Xt[c * PK + l8]) = pack8(cf);
  }
  __syncthreads();
  // per-channel mu partials (2 threads/channel)
  {
    int c = tid >> 1, half = tid & 1;
    float s = 0.f;
    for (int l = half * 64; l < half * 64 + 64; ++l)
      s += b2f(Xt[c * PK + l]);
    s += __shfl_xor(s, 1, 64);
    if (half == 0) mupartC[(size_t)chunk * CDIM + c] = s;
  }
  f32x4 acc[4][4];
#pragma unroll
  for (int m = 0; m < 4; ++m)
#pragma unroll
    for (int n = 0; n < 4; ++n) acc[m][n] = (f32x4){0.f, 0.f, 0.f, 0.f};
#pragma unroll
  for (int kk = 0; kk < 4; ++kk) {
    int kof = kk * 32 + rg * 8;
    bf16x8 a[4], bfr[4];
#pragma unroll
    for (int m = 0; m < 4; ++m)
      a[m] = *(const bf16x8*)(&Xt[(wm * 64 + m * 16 + cl) * PK + kof]);
#pragma unroll
    for (int n = 0; n < 4; ++n)
      bfr[n] = *(const bf16x8*)(&Xt[(wn * 64 + n * 16 + cl) * PK + kof]);
#pragma unroll
    for (int m = 0; m < 4; ++m)
#pragma unroll
      for (int n = 0; n < 4; ++n)
        acc[m][n] = __builtin_amdgcn_mfma_f32_16x16x32_bf16(bfr[n], a[m], acc[m][n], 0, 0, 0);
  }
  float* pb = part + (size_t)chunk * CDIM * CDIM;
#pragma unroll
  for (int m = 0; m < 4; ++m) {
    int c = wm * 64 + m * 16 + cl;
#pragma unroll
    for (int n = 0; n < 4; ++n) {
      int d0 = wn * 64 + n * 16 + rg * 4;
      float v[4] = {acc[m][n][0], acc[m][n][1], acc[m][n][2], acc[m][n][3]};
      stv4(&pb[c * CDIM + d0], v);
    }
  }
}

// ---------------- reduce mu partials ----------------
__global__ __launch_bounds__(TPB) void k_muredC(const float* __restrict__ mupartC,
                                                float* __restrict__ mu) {
  int c = blockIdx.x;
  int tid = threadIdx.x;
  __shared__ float red[TPB];
  float s = 0.f;
  for (int u = tid; u < CV; u += TPB) s += mupartC[(size_t)u * CDIM + c];
  red[tid] = s;
  __syncthreads();
  for (int st = TPB / 2; st > 0; st >>= 1) {
    if (tid < st) red[tid] += red[tid + st];
    __syncthreads();
  }
  if (tid == 0) mu[c] = red[0] / HWc;
}

// ---------------- covred stage 1: 8-way slice reduce ----------------
__global__ __launch_bounds__(TPB) void k_covred1(const float* __restrict__ part,
                                                 float* __restrict__ p2) {
  int t = blockIdx.x * TPB + threadIdx.x;
  int yg = blockIdx.y;
  float s = 0.f;
  for (int p = yg * 36; p < (yg + 1) * 36; ++p)
    s += part[(size_t)p * CDIM * CDIM + t];
  p2[(size_t)yg * CDIM * CDIM + t] = s;
}
// ---------------- covred stage 2 ----------------
__global__ __launch_bounds__(TPB) void k_covred2(const float* __restrict__ p2,
                                                 const float* __restrict__ mu,
                                                 float* __restrict__ cov) {
  int t = blockIdx.x * TPB + threadIdx.x;
  if (t >= CDIM * CDIM) return;
  float s = 0.f;
#pragma unroll
  for (int y = 0; y < 8; ++y) s += p2[(size_t)y * CDIM * CDIM + t];
  int c = t >> 7, d = t & 127;
  cov[t] = s - (float)HWc * mu[c] * mu[d];
}

// ---------------- parallel stable rank ----------------
__global__ __launch_bounds__(CDIM) void k_rank(const float* __restrict__ cov,
                                               int* __restrict__ idx) {
  __shared__ float dsd[CDIM], score[CDIM];
  int tid = threadIdx.x;
  dsd[tid] = sqrtf(cov[tid * CDIM + tid]);
  __syncthreads();
  {
    float s = 0.f, di = dsd[tid];
    for (int d = 0; d < CDIM; ++d) s += cov[tid * CDIM + d] / (di * dsd[d]);
    score[tid] = s;
  }
  __syncthreads();
  {
    float my = score[tid];
    int rank = 0;
    for (int d = 0; d < CDIM; ++d)
      rank += (score[d] > my) || (score[d] == my && d < tid);
    idx[rank] = tid;
  }
}

// ---------------- row inverse-norms BY CHANNEL (vectorized) ----------------
__global__ __launch_bounds__(TPB) void k_norms(const bf16_t* __restrict__ qkv,
                                               float* __restrict__ invq,
                                               float* __restrict__ invk) {
  int ch = blockIdx.x, b = blockIdx.y, which = blockIdx.z;
  const bf16_t* row = qkv + ((size_t)b * C3 + which * CDIM + ch) * HWc;
  __shared__ float red[TPB];
  float s = 0.f;
  for (int u = threadIdx.x; u < HWc / 8; u += TPB)
    s += sumsq8(*(const uint4*)(&row[u * 8]));
  red[threadIdx.x] = s;
  __syncthreads();
  for (int st = TPB / 2; st > 0; st >>= 1) {
    if (threadIdx.x < st) red[threadIdx.x] += red[threadIdx.x + st];
    __syncthreads();
  }
  if (threadIdx.x == 0) {
    float n = fmaxf(sqrtf(red[0]), 1e-12f);
    (which ? invk : invq)[b * CDIM + ch] = 1.f / n;
  }
}

// ---------------- QK^T split-L partials (merged groups, dynamic LDS) ----------------
template <int G>
__device__ __forceinline__ void qk2_impl(char* sm, const bf16_t* __restrict__ qkv,
                                         const int* __restrict__ idx, int start,
                                         float* __restrict__ partial, int nl, int b) {
  constexpr int RT = G / 16;
  constexpr int U  = G * CH2 / 8;
  float (*qs)[CH2 + 2] = (float (*)[CH2 + 2])sm;
  float (*ks)[CH2 + 2] = (float (*)[CH2 + 2])(sm + (size_t)G * (CH2 + 2) * 4);
  int* idxg = (int*)(sm + (size_t)2 * G * (CH2 + 2) * 4);
  int tid = threadIdx.x;
  if (tid < G) idxg[tid] = idx[start + tid];
  __syncthreads();
  int l0 = nl * CH2;
  for (int u = tid; u < U; u += TPB) {
    int r = u / (CH2 / 8), c8 = (u % (CH2 / 8)) * 8;
    int ch = idxg[r];
    uint4 vq = *(const uint4*)(&qkv[((size_t)b * C3 + ch) * HWc + l0 + c8]);
    uint4 vk = *(const uint4*)(&qkv[((size_t)b * C3 + CDIM + ch) * HWc + l0 + c8]);
    unsigned wq[4] = {vq.x, vq.y, vq.z, vq.w};
    unsigned wk[4] = {vk.x, vk.y, vk.z, vk.w};
#pragma unroll
    for (int j = 0; j < 8; ++j) {
      qs[r][c8 + j] = b2f((bf16_t)((wq[j >> 1] >> ((j & 1) * 16)) & 0xFFFFu));
      ks[r][c8 + j] = b2f((bf16_t)((wk[j >> 1] >> ((j & 1) * 16)) & 0xFFFFu));
    }
  }
  __syncthreads();
  int ti = tid & 15, tj = tid >> 4;
  float acc[RT][RT];
#pragma unroll
  for (int m = 0; m < RT; ++m)
#pragma unroll
    for (int n = 0; n < RT; ++n) acc[m][n] = 0.f;
#pragma unroll 4
  for (int l = 0; l < CH2; ++l) {
    float qa[RT], kb[RT];
#pragma unroll
    for (int m = 0; m < RT; ++m) qa[m] = qs[ti * RT + m][l];
#pragma unroll
    for (int n = 0; n < RT; ++n) kb[n] = ks[tj * RT + n][l];
#pragma unroll
    for (int m = 0; m < RT; ++m)
#pragma unroll
      for (int n = 0; n < RT; ++n) acc[m][n] += qa[m] * kb[n];
  }
  float* pb = partial + ((size_t)(b * NL2) + nl) * G * G;
#pragma unroll
  for (int m = 0; m < RT; ++m)
#pragma unroll
    for (int n = 0; n < RT; ++n)
      pb[(ti * RT + m) * G + tj * RT + n] = acc[m][n];
}

__global__ __launch_bounds__(TPB) void k_qk2g(const bf16_t* __restrict__ qkv,
                                              const int* __restrict__ idx,
                                              float* __restrict__ qkpart) {
  extern __shared__ char sm[];
  int nl = blockIdx.x, b = blockIdx.y, gi = blockIdx.z;
  if (gi == 0)      qk2_impl<16>(sm, qkv, idx, 0,  qkpart + 0,       nl, b);
  else if (gi == 1) qk2_impl<32>(sm, qkv, idx, 16, qkpart + 147456,  nl, b);
  else if (gi == 2) qk2_impl<32>(sm, qkv, idx, 48, qkpart + 737280,  nl, b);
  else              qk2_impl<48>(sm, qkv, idx, 80, qkpart + 1327104, nl, b);
}

// ---------------- QK partial reduce, stage 1: 8-way over nl ----------------
__global__ __launch_bounds__(TPB) void k_qkred1(const float* __restrict__ qkpart,
                                                float* __restrict__ qkp2) {
  int t = blockIdx.x * TPB + threadIdx.x;   // 0..9215
  int yg = blockIdx.y;                       // 0..7
  int b = t / 4608, e = t - b * 4608;
  int gi = (e < 256) ? 0 : (e < 1280) ? 1 : (e < 2304) ? 2 : 3;
  const int gg4[4]    = {256, 1024, 1024, 2304};
  const int pgoff[4]  = {0, 147456, 737280, 1327104};
  const int aoff4[4]  = {0, 256, 1280, 2304};
  int GGg = gg4[gi];
  int el = e - aoff4[gi];
  const float* pb = qkpart + pgoff[gi] + (size_t)(b * NL2) * GGg + el;
  float s = 0.f;
  for (int nl = yg * 36; nl < (yg + 1) * 36; ++nl) s += pb[(size_t)nl * GGg];
  qkp2[(size_t)yg * (BN_ * 4608) + t] = s;
}

// ---------------- softmax for all groups (sums qkp2 slices inline) ----------------
__global__ __launch_bounds__(TPB) void k_smg(const float* __restrict__ qkp2,
                                             const int* __restrict__ idx,
                                             const float* __restrict__ invq,
                                             const float* __restrict__ invk,
                                             const float* __restrict__ temperature,
                                             float* __restrict__ attS) {
  int b = blockIdx.x, gi = blockIdx.y;
  int G = dGSZ[gi], start = dGST[gi];
  int GG = G * G;
  float* as = attS + b * 4608 + dAOFF[gi];
  float temp = temperature[gi];
  __shared__ float att[2304];
  __shared__ float ivq[48], ivk[48];
  int tid = threadIdx.x;
  if (tid < G) {
    int ch = idx[start + tid];
    ivq[tid] = invq[b * CDIM + ch];
    ivk[tid] = invk[b * CDIM + ch];
  }
  __syncthreads();
  for (int e = tid; e < GG; e += TPB) {
    int base = b * 4608 + dAOFF[gi] + e;
    float s = 0.f;
#pragma unroll
    for (int y = 0; y < 8; ++y) s += qkp2[(size_t)y * (BN_ * 4608) + base];
    int i = e / G, j = e - i * G;
    att[e] = s * temp * ivq[i] * ivk[j];
  }
  __syncthreads();
  if (tid < G) {
    float mx = -3.4e38f;
    for (int j = 0; j < G; ++j) mx = fmaxf(mx, att[tid * G + j]);
    float ssum = 0.f;
    for (int j = 0; j < G; ++j) { float ex = expf(att[tid * G + j] - mx); att[tid * G + j] = ex; ssum += ex; }
    float inv = 1.f / ssum;
    for (int j = 0; j < G; ++j) att[tid * G + j] *= inv;
  }
  __syncthreads();
  for (int e = tid; e < GG; e += TPB) as[e] = att[e];
}

// ---------------- column-parallel group MLP ----------------
__global__ __launch_bounds__(TPB) void k_imlpg(const float* __restrict__ attS,
                                               const float* __restrict__ qv_cache,
                                               const float* __restrict__ cw0, const float* __restrict__ cb0,
                                               const float* __restrict__ gw0, const float* __restrict__ gb0,
                                               const float* __restrict__ cw1, const float* __restrict__ cb1,
                                               const float* __restrict__ gw1, const float* __restrict__ gb1,
                                               const float* __restrict__ cw2, const float* __restrict__ cb2,
                                               const float* __restrict__ gw2, const float* __restrict__ gb2,
                                               const float* __restrict__ cw3, const float* __restrict__ cb3,
                                               const float* __restrict__ gw3, const float* __restrict__ gb3,
                                               float* __restrict__ attF) {
  int b = blockIdx.x, gi = blockIdx.y, tile = blockIdx.z;
  int G = dGSZ[gi];
  int p0 = tile * 16;
  if (p0 >= G) return;
  int GG = G * G;
  const float* cw_w = (gi == 0) ? cw0 : (gi == 1) ? cw1 : (gi == 2) ? cw2 : cw3;
  const float* cw_b = (gi == 0) ? cb0 : (gi == 1) ? cb1 : (gi == 2) ? cb2 : cb3;
  const float* g_w  = (gi == 0) ? gw0 : (gi == 1) ? gw1 : (gi == 2) ? gw2 : gw3;
  const float* g_b  = (gi == 0) ? gb0 : (gi == 1) ? gb1 : (gi == 2) ? gb2 : gb3;
  const float* as = attS + b * 4608 + dAOFF[gi];
  float* af = attF + dABASE[gi] + (size_t)b * GG;
  int tid = threadIdx.x;
  __shared__ float cwW[2 * 48 * 48];
  __shared__ float gW[48 * 48];
  __shared__ float attC[48 * 16], t1C[48 * 16], scC[48 * 16], shC[48 * 16],
                   x1pC[48 * 16], t2C[48 * 16];
  for (int e = tid; e < 2 * G * G; e += TPB) cwW[e] = cw_w[e];
  for (int e = tid; e < G * G; e += TPB) gW[e] = g_w[e];
  for (int u = tid; u < G * 16; u += TPB) {
    int c = u >> 4, pl = u & 15;
    int p = p0 + pl;
    float av = 0.f, pv = 0.f;
    if (p < G) {
      av = as[c * G + p];
      int so = c * CDIM / G, eo = ((c + 1) * CDIM + G - 1) / G;
      int sp = p * CDIM / G, ep = ((p + 1) * CDIM + G - 1) / G;
      float ssum = 0.f;
      for (int i2 = so; i2 < eo; ++i2)
        for (int j2 = sp; j2 < ep; ++j2) ssum += qv_cache[i2 * CDIM + j2];
      pv = ssum / (float)((eo - so) * (ep - sp));
    }
    attC[u] = av;
    t1C[u] = pv + av;
  }
  __syncthreads();
  for (int u = tid; u < 2 * G * 16; u += TPB) {
    int o = u >> 4, pl = u & 15;
    float acc = cw_b[o];
    for (int c = 0; c < G; ++c) acc += cwW[o * G + c] * t1C[c * 16 + pl];
    if (o < G) scC[o * 16 + pl] = acc;
    else       shC[(o - G) * 16 + pl] = acc;
  }
  __syncthreads();
  for (int u = tid; u < G * 16; u += TPB)
    x1pC[u] = attC[u] * scC[u] + shC[u];
  __syncthreads();
  for (int u = tid; u < G * 16; u += TPB) {
    int o = u >> 4, pl = u & 15;
    float acc = g_b[o];
    for (int c = 0; c < G; ++c) acc += gW[o * G + c] * x1pC[c * 16 + pl];
    t2C[u] = acc;
  }
  __syncthreads();
  for (int u = tid; u < G * 16; u += TPB) {
    int c = u >> 4, pl = u & 15;
    int p = p0 + pl;
    if (p < G)
      af[c * G + p] = x1pC[u] * gelu_f(t2C[u]) + attC[u];
  }
}

// ---------------- att @ V (MFMA) + (qn+kn) fused, merged groups ----------------
template <int G, int GP>
__device__ __forceinline__ void av2_impl(char* sm, const bf16_t* __restrict__ qkv,
                                         const int* __restrict__ idx,
                                         const float* __restrict__ attF,
                                         const float* __restrict__ invq,
                                         const float* __restrict__ invk, int start,
                                         bf16_t* __restrict__ out_all,
                                         bf16_t* __restrict__ s_buf, int l0, int b) {
  constexpr int PK = GP + 8;
  constexpr int MT = G / 16;
  bf16_t* Vt = (bf16_t*)sm;                                     // [128][PK]
  bf16_t* Ab = (bf16_t*)(sm + (size_t)128 * PK * 2);            // [G][PK]
  int* idxg  = (int*)(sm + (size_t)128 * PK * 2 + (size_t)G * PK * 2);
  int tid = threadIdx.x, lane = tid & 63, wid = tid >> 6;
  int cl = lane & 15, rg = lane >> 4;
  if (tid < G) idxg[tid] = idx[start + tid];
  __syncthreads();
  for (int u = tid; u < (GP / 2) * 16; u += TPB) {
    int j2 = u % (GP / 2), lb = u / (GP / 2);
    int ja = j2 * 2;
    uint4 rA = {0u,0u,0u,0u}, rB = {0u,0u,0u,0u};
    if (ja < G)     rA = *(const uint4*)(&qkv[((size_t)b * C3 + 2 * CDIM + idxg[ja]) * HWc + l0 + lb * 8]);
    if (ja + 1 < G) rB = *(const uint4*)(&qkv[((size_t)b * C3 + 2 * CDIM + idxg[ja + 1]) * HWc + l0 + lb * 8]);
    unsigned wa[4] = {rA.x, rA.y, rA.z, rA.w};
    unsigned wb[4] = {rB.x, rB.y, rB.z, rB.w};
#pragma unroll
    for (int j = 0; j < 8; ++j) {
      unsigned va = (wa[j >> 1] >> ((j & 1) * 16)) & 0xFFFFu;
      unsigned vb = (wb[j >> 1] >> ((j & 1) * 16)) & 0xFFFFu;
      *(unsigned*)(&Vt[(lb * 8 + j) * PK + ja]) = va | (vb << 16);
    }
  }
  for (int e = tid; e < G * GP; e += TPB) {
    int p = e / GP, j = e - p * GP;
    Ab[p * PK + j] = (j < G) ? f2b(attF[(size_t)b * G * G + p * G + j]) : (bf16_t)0;
  }
  __syncthreads();
  f32x4 acc[MT][2];
#pragma unroll
  for (int m = 0; m < MT; ++m)
#pragma unroll
    for (int n = 0; n < 2; ++n) acc[m][n] = (f32x4){0.f, 0.f, 0.f, 0.f};
#pragma unroll
  for (int kk = 0; kk < GP / 32; ++kk) {
    int kof = kk * 32 + rg * 8;
    bf16x8 a[MT], bfr[2];
#pragma unroll
    for (int m = 0; m < MT; ++m)
      a[m] = *(const bf16x8*)(&Ab[(m * 16 + cl) * PK + kof]);
#pragma unroll
    for (int n = 0; n < 2; ++n)
      bfr[n] = *(const bf16x8*)(&Vt[(wid * 32 + n * 16 + cl) * PK + kof]);
#pragma unroll
    for (int m = 0; m < MT; ++m)
#pragma unroll
      for (int n = 0; n < 2; ++n)
        acc[m][n] = __builtin_amdgcn_mfma_f32_16x16x32_bf16(bfr[n], a[m], acc[m][n], 0, 0, 0);
  }
#pragma unroll
  for (int m = 0; m < MT; ++m) {
    int p = m * 16 + cl;
    int pg = start + p;
    int ch = idxg[p];
    float iq = invq[b * CDIM + ch], ik = invk[b * CDIM + ch];
#pragma unroll
    for (int n = 0; n < 2; ++n) {
      int lg = l0 + wid * 32 + n * 16 + rg * 4;
      float q4[4], k4[4];
      ldv4(&qkv[((size_t)b * C3 + ch) * HWc + lg], q4);
      ldv4(&qkv[((size_t)b * C3 + CDIM + ch) * HWc + lg], k4);
      float vo[4], vs[4];
#pragma unroll
      for (int r = 0; r < 4; ++r) {
        vo[r] = acc[m][n][r];
        vs[r] = vo[r] + q4[r] * iq + k4[r] * ik;
      }
      size_t off = ((size_t)b * CDIM + pg) * HWc + lg;
      stv4(&out_all[off], vo);
      stv4(&s_buf[off], vs);
    }
  }
}

__global__ __launch_bounds__(TPB) void k_avg(const bf16_t* __restrict__ qkv,
                                             const int* __restrict__ idx,
                                             const float* __restrict__ atts,
                                             const float* __restrict__ invq,
                                             const float* __restrict__ invk,
                                             bf16_t* __restrict__ out_all,
                                             bf16_t* __restrict__ s_buf) {
  extern __shared__ char sm[];
  int l0 = blockIdx.x * 128, b = blockIdx.y, gi = blockIdx.z;
  if (gi == 0)      av2_impl<16, 32>(sm, qkv, idx, atts + 0,    invq, invk, 0,  out_all, s_buf, l0, b);
  else if (gi == 1) av2_impl<32, 32>(sm, qkv, idx, atts + 512,  invq, invk, 16, out_all, s_buf, l0, b);
  else if (gi == 2) av2_impl<32, 32>(sm, qkv, idx, atts + 2560, invq, invk, 48, out_all, s_buf, l0, b);
  else              av2_impl<48, 64>(sm, qkv, idx, atts + 4608, invq, invk, 80, out_all, s_buf, l0, b);
}

// ---------------- qv_new: bilinear upsample + floor + EMA ----------------
__global__ __launch_bounds__(TPB) void k_qvnew(const float* __restrict__ attsF,
                                               const float* __restrict__ qv_cache,
                                               float* __restrict__ out_qv) {
  int t = blockIdx.x * TPB + threadIdx.x;
  if (t >= CDIM * CDIM) return;
  int r = t >> 7, cq = t & 127;
  const int gs[4]   = {16, 32, 32, 48};
  const int base[4] = {0, 512, 2560, 4608};
  float acc = 0.f;
  for (int gi = 0; gi < 4; ++gi) {
    int g = gs[gi], gg = g * g;
    const float* a0 = attsF + base[gi];
    float scale = (float)g / CDIM;
    float fr = (r + 0.5f) * scale - 0.5f;
    float fc = (cq + 0.5f) * scale - 0.5f;
    float flr = floorf(fr), flc = floorf(fc);
    int i0 = (int)flr, j0 = (int)flc;
    float wr = fr - flr, wcw = fc - flc;
    int i0c = max(i0, 0), i1c = min(i0 + 1, g - 1);
    int j0c = max(j0, 0), j1c = min(j0 + 1, g - 1);
    float m00 = 0.5f * (a0[i0c * g + j0c] + a0[gg + i0c * g + j0c]);
    float m01 = 0.5f * (a0[i0c * g + j1c] + a0[gg + i0c * g + j1c]);
    float m10 = 0.5f * (a0[i1c * g + j0c] + a0[gg + i1c * g + j0c]);
    float m11 = 0.5f * (a0[i1c * g + j1c] + a0[gg + i1c * g + j1c]);
    float val = (1.f - wr) * ((1.f - wcw) * m00 + wcw * m01)
              + wr * ((1.f - wcw) * m10 + wcw * m11);
    acc += floorf(val);
  }
  out_qv[t] = qv_cache[t] * 0.9f + acc * 0.1f;
}

// ---------------- ffn: dw3 pair + gelu-gate, 2 rows x 8 px per thread ----------------
__global__ __launch_bounds__(TPB) void k_dwgeluv(const bf16_t* __restrict__ y0c,
                                                 const float* __restrict__ wt,
                                                 bf16_t* __restrict__ z,
                                                 int Cc, int c0, long totalG) {
  long t = (long)blockIdx.x * TPB + threadIdx.x;
  if (t >= totalG) return;
  int g = (int)(t % (HWc / 16));
  long bc = t / (HWc / 16);
  int cl = (int)(bc % Cc);
  int b = (int)(bc / Cc);
  int rp = g / (WW / 8), w8 = (g % (WW / 8)) * 8;
  int h = rp * 2;
  const bf16_t* i1 = y0c + ((size_t)b * 2 * Cc + cl) * HWc;
  const bf16_t* i2 = i1 + (size_t)Cc * HWc;
  const float* w1 = wt + (size_t)(c0 + cl) * 9;
  const float* w2 = wt + (size_t)(HID + c0 + cl) * 9;
  float rv[4][10];
#pragma unroll
  for (int dy = 0; dy < 4; ++dy) {
    int hh = h - 1 + dy;
    if (hh < 0 || hh >= HH) {
#pragma unroll
      for (int j = 0; j < 10; ++j) rv[dy][j] = 0.f;
    } else {
      dwrow(i1 + hh * WW + w8, w8, rv[dy]);
    }
  }
  float g0[8], g1[8];
#pragma unroll
  for (int j = 0; j < 8; ++j) {
    float s0 = 0.f, s1 = 0.f;
#pragma unroll
    for (int dy = 0; dy < 3; ++dy)
#pragma unroll
      for (int dx = 0; dx < 3; ++dx) {
        float wv = w1[dy * 3 + dx];
        s0 += rv[dy][j + dx] * wv;
        s1 += rv[dy + 1][j + dx] * wv;
      }
    g0[j] = gelu_f(s0); g1[j] = gelu_f(s1);
  }
#pragma unroll
  for (int dy = 0; dy < 4; ++dy) {
    int hh = h - 1 + dy;
    if (hh < 0 || hh >= HH) {
#pragma unroll
      for (int j = 0; j < 10; ++j) rv[dy][j] = 0.f;
    } else {
      dwrow(i2 + hh * WW + w8, w8, rv[dy]);
    }
  }
  float o0[8], o1[8];
#pragma unroll
  for (int j = 0; j < 8; ++j) {
    float s0 = 0.f, s1 = 0.f;
#pragma unroll
    for (int dy = 0; dy < 3; ++dy)
#pragma unroll
      for (int dx = 0; dx < 3; ++dx) {
        float wv = w2[dy * 3 + dx];
        s0 += rv[dy][j + dx] * wv;
        s1 += rv[dy + 1][j + dx] * wv;
      }
    o0[j] = g0[j] * s0; o1[j] = g1[j] * s1;
  }
  bf16_t* zp = z + ((size_t)b * HID + c0 + cl) * HWc + h * WW + w8;
  *(uint4*)zp = pack8(o0);
  *(uint4*)(zp + WW) = pack8(o1);
}

// ---------------- host ----------------
extern "C" void kernel_launch(void* const* d_in, const int* in_sizes, int n_in,
                              void* d_out, int out_size, void* d_ws, size_t ws_size,
                              hipStream_t stream) {
  if (ws_size < WS_NEED) return;  // workspace insufficient

  const float* x        = (const float*)d_in[0];
  const float* qv_cache = (const float*)d_in[1];
  const float* ln1_w    = (const float*)d_in[2];
  const float* ln1_b    = (const float*)d_in[3];
  const float* ln2_w    = (const float*)d_in[4];
  const float* ln2_b    = (const float*)d_in[5];
  const float* temperature = (const float*)d_in[6];
  const float* w_qkv    = (const float*)d_in[7];
  const float* w_qkv_dw = (const float*)d_in[8];
  const float* w_proj   = (const float*)d_in[9];
  const float* intra_down_w = (const float*)d_in[10];
  const float* intra_down_b = (const float*)d_in[11];
  const float* intra_up_w   = (const float*)d_in[12];
  const float* intra_up_b   = (const float*)d_in[13];
  const float* intra_gate_w = (const float*)d_in[14];
  const float* intra_gate_b = (const float*)d_in[15];
  const float* ffn_in_w  = (const float*)d_in[32];
  const float* ffn_dw_w  = (const float*)d_in[33];
  const float* ffn_out_w = (const float*)d_in[34];

  char* wsb = (char*)d_ws;
  float* out    = (float*)d_out;
  float* out_qv = out + (size_t)BN_ * CDIM * HWc;
  bf16_t* xn2   = (bf16_t*)d_out;

  float*  attS    = (float*)(wsb + oATTS2);
  bf16_t* wb      = (bf16_t*)(wsb + oWB);
  float*  qkp2    = (float*)(wsb + oQKP2);
  float*  mupartC = (float*)(wsb + oMUPC);
  float*  atts    = (float*)(wsb + oATTS);
  float*  invqA   = (float*)(wsb + oNORMQ);
  float*  invkA   = (float*)(wsb + oNORMK);
  int*    idx     = (int*)(wsb + oIDX);
  float*  mu      = (float*)(wsb + oMU);
  float*  cov     = (float*)(wsb + oCOV);
  bf16_t* qkv     = (bf16_t*)(wsb + oQKV);
  bf16_t* xn      = (bf16_t*)(wsb + oXN);
  bf16_t* out_all = (bf16_t*)(wsb + oOUTALL);
  bf16_t* sbuf    = (bf16_t*)(wsb + oSBUF);
  bf16_t* chunk1  = (bf16_t*)(wsb + oCHUNK1);
  float*  covpart = (float*)(wsb + oCOVPART);
  float*  covp2   = (float*)(wsb + oCOVP2);
  float*  qkpart  = (float*)(wsb + oQKPART);
  bf16_t* x1b     = (bf16_t*)(wsb + oX1B);
  bf16_t* y0c     = (bf16_t*)(wsb + oY0C);
  bf16_t* zbuf    = (bf16_t*)(wsb + oZ);

  const bf16_t* wq_b   = wb + eWQ;
  const bf16_t* ffi_b  = wb + eFFI;
  const bf16_t* ffo_b  = wb + eFFO;

  const int GX = HWc / 128;
  const int NOS = 1 << 30;
  dim3 gA(GX, BN_);

  // allow >64 KB dynamic LDS for the fused MLP kernel (once)
  static bool s_attr = false;
  if (!s_attr) {
    hipFuncSetAttribute((const void*)k_mlp4,
                        hipFuncAttributeMaxDynamicSharedMemorySize, 105472);
    s_attr = true;
  }

  // 0. pre-convert weights fp32->bf16
  k_wcvt<<<(eTOT + TPB - 1) / TPB, TPB, 0, stream>>>(
      w_qkv, intra_gate_w, intra_down_w, intra_up_w, w_proj, ffn_in_w, ffn_out_w, wb);

  // 1. LN1: xn = LN(x)
  k_ln<float><<<(BN_ * HWc + TPB - 1) / TPB, TPB, 0, stream>>>(x, ln1_w, ln1_b, xn);

  // 2+3. qkv = dw3(c1x1(xn, w_qkv)) in 2 chunks of 192 channels
  for (int ci = 0; ci < 2; ++ci) {
    int c0 = ci * 192;
    k_mgA<bf16_t, float, 128, 0><<<gA, TPB, 0, stream>>>(
        wq_b + (size_t)c0 * CDIM, wq_b, NOS, nullptr, xn, nullptr, chunk1,
        192, CDIM, 192, 0);
    long totG = (long)BN_ * 192 * (HWc / 16);
    k_dw3v<<<(unsigned)((totG + TPB - 1) / TPB), TPB, 0, stream>>>(
        chunk1, w_qkv_dw, qkv, 192, c0, C3, totG);
  }

  // 4. inverse norms by channel (no idx dependency)
  k_norms<<<dim3(CDIM, BN_, 2), TPB, 0, stream>>>(qkv, invqA, invkA);

  // 5-7. correlation sort (cov + mu in one pass)
  k_cov4<<<CV, TPB, 0, stream>>>(qkv, covpart, mupartC);
  k_muredC<<<CDIM, TPB, 0, stream>>>(mupartC, mu);
  k_covred1<<<dim3(64, 8), TPB, 0, stream>>>(covpart, covp2);
  k_covred2<<<64, TPB, 0, stream>>>(covp2, mu, cov);
  k_rank<<<1, CDIM, 0, stream>>>(cov, idx);

  // 9. QK^T partials for all 4 groups in ONE dispatch
  {
    size_t dyn = (size_t)2 * 48 * (CH2 + 2) * 4 + 48 * 4;
    k_qk2g<<<dim3(NL2, BN_, 4), TPB, dyn, stream>>>(qkv, idx, qkpart);
  }
  // 10. reduce stage 1 -> qkp2 (stage 2 folded into softmax)
  k_qkred1<<<dim3(36, 8), TPB, 0, stream>>>(qkpart, qkp2);
  // 11. softmax (sums qkp2 inline) -> attS
  k_smg<<<dim3(BN_, 4), TPB, 0, stream>>>(qkp2, idx, invqA, invkA, temperature, attS);
  // 12. column-parallel group MLP -> attF
  k_imlpg<<<dim3(BN_, 4, 3), TPB, 0, stream>>>(
      attS, qv_cache,
      (const float*)d_in[16], (const float*)d_in[17], (const float*)d_in[18], (const float*)d_in[19],
      (const float*)d_in[20], (const float*)d_in[21], (const float*)d_in[22], (const float*)d_in[23],
      (const float*)d_in[24], (const float*)d_in[25], (const float*)d_in[26], (const float*)d_in[27],
      (const float*)d_in[28], (const float*)d_in[29], (const float*)d_in[30], (const float*)d_in[31],
      atts);
  // 13. att@V (MFMA) + s
  {
    size_t dyn = (size_t)128 * 72 * 2 + (size_t)48 * 72 * 2 + 48 * 4;
    k_avg<<<dim3(HWc / 128, BN_, 4), TPB, dyn, stream>>>(
        qkv, idx, atts, invqA, invkA, out_all, sbuf);
  }
  // qv_new
  k_qvnew<<<(CDIM * CDIM + TPB - 1) / TPB, TPB, 0, stream>>>(atts, qv_cache, out_qv);

  // fused gate->down->up->proj: x1b = x + proj(up(down(gated)) + out_all)
  k_mlp4<<<gA, TPB, 105472, stream>>>(
      wb, intra_gate_b, intra_down_b, intra_up_b, sbuf, out_all, x, x1b);

  // LN2: xn2 = LN(x1b)
  k_ln<bf16_t><<<(BN_ * HWc + TPB - 1) / TPB, TPB, 0, stream>>>(x1b, ln2_w, ln2_b, xn2);

  // FFN in 3 chunks (y0c <= 33.6 MB in outall span; z full in qkv span)
  const int fcc[3] = {114, 114, 112};
  const int fc0[3] = {0, 114, 228};
  for (int ci = 0; ci < 3; ++ci) {
    int Cc = fcc[ci], c0 = fc0[ci];
    k_mgA<bf16_t, float, 128, 0><<<gA, TPB, 0, stream>>>(
        ffi_b + (size_t)c0 * CDIM, ffi_b + (size_t)(HID + c0) * CDIM, Cc,
        nullptr, xn2, nullptr, y0c, 2 * Cc, CDIM, 2 * Cc, 0);
    long totG = (long)BN_ * Cc * (HWc / 16);
    k_dwgeluv<<<(unsigned)((totG + TPB - 1) / TPB), TPB, 0, stream>>>(
        y0c, ffn_dw_w, zbuf, Cc, c0, totG);
  }
  // out = x1b + c1x1(z, ffn_out_w)
  k_mgB<float, bf16_t, 1><<<gA, TPB, 0, stream>>>(
      ffo_b, nullptr, zbuf, x1b, out, CDIM, HID, HID, CDIM, CDIM);
}

// Round 21
// 512.739 us; speedup vs baseline: 1.0258x; 1.0258x over previous
//
#include <hip/hip_runtime.h>
#include <math.h>

#define TPB 256

constexpr int BN_  = 2;
constexpr int CDIM = 128;
constexpr int HH   = 192;
constexpr int WW   = 192;
constexpr int HWc  = HH * WW;      // 36864
constexpr int C3   = 384;
constexpr int HID  = 340;
constexpr int NL2  = 288;          // split-L chunks for QK^T
constexpr int CH2  = HWc / NL2;    // 128
constexpr int CV   = 288;          // split-L chunks for cov (128 cols each)

typedef unsigned short bf16_t;
typedef __attribute__((ext_vector_type(8))) __bf16 bf16x8;
typedef __attribute__((ext_vector_type(4))) float f32x4;

__device__ __forceinline__ float b2f(bf16_t v) {
  unsigned u = ((unsigned)v) << 16;
  return __uint_as_float(u);
}
__device__ __forceinline__ bf16_t f2b(float f) {
  unsigned u = __float_as_uint(f);
  unsigned r = (u + 0x7FFFu + ((u >> 16) & 1u)) >> 16;
  return (bf16_t)r;
}
__device__ __forceinline__ float ldf(const float* p) { return *p; }
__device__ __forceinline__ float ldf(const bf16_t* p) { return b2f(*p); }
__device__ __forceinline__ void stf(float* p, float v) { *p = v; }
__device__ __forceinline__ void stf(bf16_t* p, float v) { *p = f2b(v); }

__device__ __forceinline__ void ldv4(const float* p, float* v) {
  float4 t = *(const float4*)p;
  v[0] = t.x; v[1] = t.y; v[2] = t.z; v[3] = t.w;
}
__device__ __forceinline__ void ldv4(const bf16_t* p, float* v) {
  ushort4 t = *(const ushort4*)p;
  v[0] = b2f(t.x); v[1] = b2f(t.y); v[2] = b2f(t.z); v[3] = b2f(t.w);
}
__device__ __forceinline__ void stv4(float* p, const float* v) {
  float4 t; t.x = v[0]; t.y = v[1]; t.z = v[2]; t.w = v[3];
  *(float4*)p = t;
}
__device__ __forceinline__ void stv4(bf16_t* p, const float* v) {
  ushort4 t; t.x = f2b(v[0]); t.y = f2b(v[1]); t.z = f2b(v[2]); t.w = f2b(v[3]);
  *(ushort4*)p = t;
}

__device__ __forceinline__ float gelu_f(float x) {
  return 0.5f * x * (1.0f + erff(x * 0.7071067811865475f));
}

__device__ __forceinline__ void unpack8(uint4 v, float* rv) {
  unsigned wv[4] = {v.x, v.y, v.z, v.w};
#pragma unroll
  for (int j = 0; j < 8; ++j)
    rv[j + 1] = b2f((bf16_t)((wv[j >> 1] >> ((j & 1) * 16)) & 0xFFFFu));
}
__device__ __forceinline__ uint4 pack8(const float* a) {
  uint4 o;
  unsigned w[4];
#pragma unroll
  for (int p = 0; p < 4; ++p) {
    unsigned lo = f2b(a[2 * p]), hi = f2b(a[2 * p + 1]);
    w[p] = lo | (hi << 16);
  }
  o.x = w[0]; o.y = w[1]; o.z = w[2]; o.w = w[3];
  return o;
}
__device__ __forceinline__ float sumsq8(uint4 v) {
  unsigned w[4] = {v.x, v.y, v.z, v.w};
  float s = 0.f;
#pragma unroll
  for (int j = 0; j < 8; ++j) {
    float t = b2f((bf16_t)((w[j >> 1] >> ((j & 1) * 16)) & 0xFFFFu));
    s += t * t;
  }
  return s;
}

// load a 10-wide window (8-aligned interior + 2 edges) for depthwise rows
__device__ __forceinline__ void dwrow(const bf16_t* rp, int w8, float* rv) {
  unpack8(*(const uint4*)rp, rv);
  rv[0] = (w8 > 0) ? b2f(rp[-1]) : 0.f;
  rv[9] = (w8 + 8 < WW) ? b2f(rp[8]) : 0.f;
}

// group tables
__device__ __constant__ int dGSZ[4]   = {16, 32, 32, 48};
__device__ __constant__ int dGST[4]   = {0, 16, 48, 80};
__device__ __constant__ int dAOFF[4]  = {0, 256, 1280, 2304};   // attraw/attS slots
__device__ __constant__ int dABASE[4] = {0, 512, 2560, 4608};   // attF (b-interleaved)

// ---------------- workspace layout (byte offsets) ----------------
constexpr size_t oATTS2   = 65536;
constexpr size_t oWB      = 131072;            // bf16 weight arena (468,992 B)
constexpr size_t oQKP2    = 602112;            // qk 2-stage partials (294,912 B)
constexpr size_t oMUPC    = 897024;            // cov mu partials 288*128 fp32 (147,456 B)
constexpr size_t oATTS    = 1327104;           // attF
constexpr size_t oNORMQ   = 1363968;           // stores 1/norm (by channel)
constexpr size_t oNORMK   = 1364992;           // stores 1/norm (by channel)
constexpr size_t oIDX     = 1366016;
constexpr size_t oMU      = 1366528;
constexpr size_t oCOV     = 1367040;
constexpr size_t oQKV     = 1572864;           // 56,623,104 B
constexpr size_t oXN      = 58195968;          // 18,874,368 B  xn / qk-partials / x1b
constexpr size_t oOUTALL  = 77070336;          // 18,874,368 B
constexpr size_t oSBUF    = 95944704;          // 18,874,368 B
constexpr size_t WS_NEED  = 114819072;
// aliases:
constexpr size_t oCHUNK1  = oOUTALL;
constexpr size_t oCOVPART = oOUTALL;
constexpr size_t oCOVP2   = oSBUF;
constexpr size_t oQKPART  = oXN;
constexpr size_t oGATED   = oQKV;
constexpr size_t oDBUF    = oQKV + 18874368;
constexpr size_t oY0C     = oOUTALL;           // FFN y0c chunk (<=33.6 MB, fits 37.7 MB span)
constexpr size_t oZ       = oQKV;              // FFN z (50.1 MB, fits 56.6 MB span)
constexpr size_t oX1B     = oXN;

// bf16 weight arena element offsets
constexpr int eWQ   = 0;
constexpr int eGATE = 49152;
constexpr int eDOWN = 65536;
constexpr int eUP   = 73728;
constexpr int ePROJ = 81920;
constexpr int eFFI  = 98304;
constexpr int eFFO  = 185344;
constexpr int eTOT  = 234496;

// ---------------- weight fp32->bf16 pre-conversion ----------------
__global__ __launch_bounds__(TPB) void k_wcvt(const float* __restrict__ wq,
                                              const float* __restrict__ gate,
                                              const float* __restrict__ down,
                                              const float* __restrict__ up,
                                              const float* __restrict__ proj,
                                              const float* __restrict__ ffi,
                                              const float* __restrict__ ffo,
                                              bf16_t* __restrict__ wb) {
  int t = blockIdx.x * TPB + threadIdx.x;
  if (t >= eTOT) return;
  int u = t;
  if (u < 49152) { wb[eWQ + u] = f2b(wq[u]); return; }
  u -= 49152;
  if (u < 16384) { wb[eGATE + u] = f2b(gate[u]); return; }
  u -= 16384;
  if (u < 8192)  { wb[eDOWN + u] = f2b(down[u]); return; }
  u -= 8192;
  if (u < 8192)  { wb[eUP + u] = f2b(up[u]); return; }
  u -= 8192;
  if (u < 16384) { wb[ePROJ + u] = f2b(proj[u]); return; }
  u -= 16384;
  if (u < 87040) { wb[eFFI + u] = f2b(ffi[u]); return; }
  u -= 87040;
  {
    int o = u / 384, k = u - o * 384;
    wb[eFFO + u] = (k < HID) ? f2b(ffo[o * HID + k]) : (bf16_t)0;
  }
}

// ---------------- LayerNorm over channel dim (templated input) ----------------
template <typename TI>
__global__ __launch_bounds__(TPB) void k_ln(const TI* __restrict__ x,
                                            const float* __restrict__ w,
                                            const float* __restrict__ bias,
                                            bf16_t* __restrict__ out) {
  int t = blockIdx.x * TPB + threadIdx.x;
  if (t >= BN_ * HWc) return;
  int b = t / HWc, l = t - b * HWc;
  const TI* xb = x + (size_t)b * CDIM * HWc + l;
  float s = 0.f, s2 = 0.f;
#pragma unroll 4
  for (int c = 0; c < CDIM; ++c) { float v = ldf(&xb[(size_t)c * HWc]); s += v; s2 += v * v; }
  float mu  = s * (1.f / CDIM);
  float var = s2 * (1.f / CDIM) - mu * mu;
  float inv = 1.f / sqrtf(var + 1e-5f);
  bf16_t* ob = out + (size_t)b * CDIM * HWc + l;
#pragma unroll 4
  for (int c = 0; c < CDIM; ++c)
    stf(&ob[(size_t)c * HWc], (ldf(&xb[(size_t)c * HWc]) - mu) * inv * w[c] + bias[c]);
}

// ============ MFMA channel GEMM, ACT-RESIDENT (K = KT <= 128), 128-l tile ============
// EPI: 0 = (+bias), 1 = (+bias)+aux, 2 = gelu(+bias)*aux, 3 = gelu(+bias)*At (aux==in)
template <typename TO, typename TA, int KT, int EPI>
__global__ __launch_bounds__(TPB) void k_mgA(const bf16_t* __restrict__ W,
                                             const bf16_t* __restrict__ W2, int osplit,
                                             const float* __restrict__ bias,
                                             const bf16_t* __restrict__ in,
                                             const TA* __restrict__ aux,
                                             TO* __restrict__ out, int O,
                                             int ibr, int obr, int abr) {
  constexpr int L  = HWc;
  constexpr int PK = KT + 8;
  constexpr int KH = KT / 2;
  constexpr int SH = (KT == 128) ? 6 : 5;
  __shared__ bf16_t At[128 * PK];
  __shared__ bf16_t Wt[64 * PK];
  int b = blockIdx.y;
  const bf16_t* inb  = in  + (size_t)b * ibr * L;
  const TA*     auxb = aux ? aux + (size_t)b * abr * L : nullptr;
  TO*           outb = out + (size_t)b * obr * L;
  int l0 = blockIdx.x * 128;
  int tid = threadIdx.x, lane = tid & 63, wid = tid >> 6;
  int wm = wid >> 1, wn = wid & 1;
  int cl = lane & 15, rg = lane >> 4;

#pragma unroll
  for (int r = 0; r < (KH * 16) / TPB; ++r) {
    int u  = tid + r * TPB;
    int k2 = u & (KH - 1), lb = u >> SH;
    int ka = k2 * 2;
    uint4 rowA = *(const uint4*)(&inb[(size_t)ka * L + l0 + lb * 8]);
    uint4 rowB = *(const uint4*)(&inb[(size_t)(ka + 1) * L + l0 + lb * 8]);
    unsigned wa[4] = {rowA.x, rowA.y, rowA.z, rowA.w};
    unsigned wb[4] = {rowB.x, rowB.y, rowB.z, rowB.w};
#pragma unroll
    for (int j = 0; j < 8; ++j) {
      unsigned va = (wa[j >> 1] >> ((j & 1) * 16)) & 0xFFFFu;
      unsigned vb = (wb[j >> 1] >> ((j & 1) * 16)) & 0xFFFFu;
      *(unsigned*)(&At[(lb * 8 + j) * PK + ka]) = va | (vb << 16);
    }
  }

  int noc = (O + 63) >> 6;
  for (int oc = 0; oc < noc; ++oc) {
    int o0 = oc * 64;
#pragma unroll
    for (int r = 0; r < (64 * KT / 8) / TPB; ++r) {
      int e = tid + r * TPB;
      int o = e / (KT / 8), k8 = (e % (KT / 8)) * 8;
      int og = o0 + o;
      uint4 wv = {0u, 0u, 0u, 0u};
      if (og < O) {
        const bf16_t* wrow = (og < osplit) ? (W + (size_t)og * KT)
                                           : (W2 + (size_t)(og - osplit) * KT);
        wv = *(const uint4*)(&wrow[k8]);
      }
      *(uint4*)(&Wt[o * PK + k8]) = wv;
    }
    __syncthreads();
    f32x4 acc[2][4];
#pragma unroll
    for (int m = 0; m < 2; ++m)
#pragma unroll
      for (int n = 0; n < 4; ++n) acc[m][n] = (f32x4){0.f, 0.f, 0.f, 0.f};
#pragma unroll
    for (int kk = 0; kk < KT / 32; ++kk) {
      int kof = kk * 32 + rg * 8;
      bf16x8 a[2], bfr[4];
#pragma unroll
      for (int m = 0; m < 2; ++m)
        a[m] = *(const bf16x8*)(&Wt[(wm * 32 + m * 16 + cl) * PK + kof]);
#pragma unroll
      for (int n = 0; n < 4; ++n)
        bfr[n] = *(const bf16x8*)(&At[(wn * 64 + n * 16 + cl) * PK + kof]);
#pragma unroll
      for (int m = 0; m < 2; ++m)
#pragma unroll
        for (int n = 0; n < 4; ++n)
          acc[m][n] = __builtin_amdgcn_mfma_f32_16x16x32_bf16(bfr[n], a[m], acc[m][n], 0, 0, 0);
    }
    __syncthreads();
#pragma unroll
    for (int m = 0; m < 2; ++m) {
      int og = o0 + wm * 32 + m * 16 + cl;
      if (og >= O) continue;
      float bv = bias ? bias[og] : 0.f;
#pragma unroll
      for (int n = 0; n < 4; ++n) {
        int lcol = l0 + wn * 64 + n * 16 + rg * 4;
        size_t off = (size_t)og * L + lcol;
        float v[4];
#pragma unroll
        for (int r = 0; r < 4; ++r) v[r] = acc[m][n][r] + bv;
        if (EPI == 1) {
          float a4[4]; ldv4(&auxb[off], a4);
#pragma unroll
          for (int r = 0; r < 4; ++r) v[r] += a4[r];
        } else if (EPI == 2) {
          float a4[4]; ldv4(&auxb[off], a4);
#pragma unroll
          for (int r = 0; r < 4; ++r) v[r] = gelu_f(v[r]) * a4[r];
        } else if (EPI == 3) {
          int lloc = wn * 64 + n * 16 + rg * 4;
#pragma unroll
          for (int r = 0; r < 4; ++r)
            v[r] = gelu_f(v[r]) * b2f(At[(lloc + r) * PK + og]);
        }
        stv4(&outb[off], v);
      }
    }
  }
}

// ============ MFMA channel GEMM, K-LOOP, O=128 in regs, 128-l tile ============
template <typename TO, typename TA, int EPI>
__global__ __launch_bounds__(TPB) void k_mgB(const bf16_t* __restrict__ Wb,
                                             const float* __restrict__ bias,
                                             const bf16_t* __restrict__ in,
                                             const TA* __restrict__ aux,
                                             TO* __restrict__ out, int O, int K,
                                             int ibr, int obr, int abr) {
  constexpr int L = HWc;
  constexpr int PK = 72, BK = 64, WSTR = 384;
  __shared__ bf16_t At[128 * PK];
  __shared__ bf16_t Wt[128 * PK];
  int b = blockIdx.y;
  const bf16_t* inb  = in  + (size_t)b * ibr * L;
  const TA*     auxb = aux ? aux + (size_t)b * abr * L : nullptr;
  TO*           outb = out + (size_t)b * obr * L;
  int l0 = blockIdx.x * 128;
  int tid = threadIdx.x, lane = tid & 63, wid = tid >> 6;
  int wm = wid >> 1, wn = wid & 1;
  int cl = lane & 15, rg = lane >> 4;

  f32x4 acc[4][4];
#pragma unroll
  for (int m = 0; m < 4; ++m)
#pragma unroll
    for (int n = 0; n < 4; ++n) acc[m][n] = (f32x4){0.f, 0.f, 0.f, 0.f};

  for (int k0 = 0; k0 < K; k0 += BK) {
#pragma unroll
    for (int r = 0; r < 2; ++r) {
      int u = tid + r * TPB;
      int k2 = u & 31, lb = u >> 5;
      int ka = k0 + k2 * 2;
      uint4 rowA = {0u,0u,0u,0u}, rowB = {0u,0u,0u,0u};
      if (ka < K)     rowA = *(const uint4*)(&inb[(size_t)ka * L + l0 + lb * 8]);
      if (ka + 1 < K) rowB = *(const uint4*)(&inb[(size_t)(ka + 1) * L + l0 + lb * 8]);
      unsigned wa[4] = {rowA.x, rowA.y, rowA.z, rowA.w};
      unsigned wb[4] = {rowB.x, rowB.y, rowB.z, rowB.w};
#pragma unroll
      for (int j = 0; j < 8; ++j) {
        unsigned va = (wa[j >> 1] >> ((j & 1) * 16)) & 0xFFFFu;
        unsigned vb = (wb[j >> 1] >> ((j & 1) * 16)) & 0xFFFFu;
        *(unsigned*)(&At[(lb * 8 + j) * PK + k2 * 2]) = va | (vb << 16);
      }
    }
#pragma unroll
    for (int r = 0; r < 4; ++r) {
      int e = tid + r * TPB;
      int o = e >> 3, k8 = (e & 7) * 8;
      uint4 wv = *(const uint4*)(&Wb[(size_t)o * WSTR + k0 + k8]);
      *(uint4*)(&Wt[o * PK + k8]) = wv;
    }
    __syncthreads();
#pragma unroll
    for (int kk = 0; kk < 2; ++kk) {
      int kof = kk * 32 + rg * 8;
      bf16x8 a[4], bfr[4];
#pragma unroll
      for (int m = 0; m < 4; ++m)
        a[m] = *(const bf16x8*)(&Wt[(wm * 64 + m * 16 + cl) * PK + kof]);
#pragma unroll
      for (int n = 0; n < 4; ++n)
        bfr[n] = *(const bf16x8*)(&At[(wn * 64 + n * 16 + cl) * PK + kof]);
#pragma unroll
      for (int m = 0; m < 4; ++m)
#pragma unroll
        for (int n = 0; n < 4; ++n)
          acc[m][n] = __builtin_amdgcn_mfma_f32_16x16x32_bf16(bfr[n], a[m], acc[m][n], 0, 0, 0);
    }
    __syncthreads();
  }
#pragma unroll
  for (int m = 0; m < 4; ++m) {
    int og = wm * 64 + m * 16 + cl;
    if (og >= O) continue;
    float bv = bias ? bias[og] : 0.f;
#pragma unroll
    for (int n = 0; n < 4; ++n) {
      int lcol = l0 + wn * 64 + n * 16 + rg * 4;
      size_t off = (size_t)og * L + lcol;
      float v[4];
#pragma unroll
      for (int r = 0; r < 4; ++r) v[r] = acc[m][n][r] + bv;
      if (EPI == 1) {
        float a4[4]; ldv4(&auxb[off], a4);
#pragma unroll
        for (int r = 0; r < 4; ++r) v[r] += a4[r];
      } else if (EPI == 2) {
        float a4[4]; ldv4(&auxb[off], a4);
#pragma unroll
        for (int r = 0; r < 4; ++r) v[r] = gelu_f(v[r]) * a4[r];
      }
      stv4(&outb[off], v);
    }
  }
}

// ---------------- depthwise 3x3 SAME, 2 rows x 8 px per thread ----------------
__global__ __launch_bounds__(TPB) void k_dw3v(const bf16_t* __restrict__ in,
                                              const float* __restrict__ wt,
                                              bf16_t* __restrict__ out,
                                              int Cc, int c0, int CoutTotal, long totalG) {
  long t = (long)blockIdx.x * TPB + threadIdx.x;
  if (t >= totalG) return;
  int g = (int)(t % (HWc / 16));
  long bc = t / (HWc / 16);
  int cl = (int)(bc % Cc);
  int b = (int)(bc / Cc);
  int rp = g / (WW / 8), w8 = (g % (WW / 8)) * 8;
  int h = rp * 2;
  const bf16_t* ib = in + ((size_t)b * Cc + cl) * HWc;
  const float* wc = wt + (size_t)(c0 + cl) * 9;
  float rv[4][10];
#pragma unroll
  for (int dy = 0; dy < 4; ++dy) {
    int hh = h - 1 + dy;
    if (hh < 0 || hh >= HH) {
#pragma unroll
      for (int j = 0; j < 10; ++j) rv[dy][j] = 0.f;
    } else {
      dwrow(ib + hh * WW + w8, w8, rv[dy]);
    }
  }
  float a0[8], a1[8];
#pragma unroll
  for (int j = 0; j < 8; ++j) {
    float s0 = 0.f, s1 = 0.f;
#pragma unroll
    for (int dy = 0; dy < 3; ++dy)
#pragma unroll
      for (int dx = 0; dx < 3; ++dx) {
        float wv = wc[dy * 3 + dx];
        s0 += rv[dy][j + dx] * wv;
        s1 += rv[dy + 1][j + dx] * wv;
      }
    a0[j] = s0; a1[j] = s1;
  }
  bf16_t* ob = out + ((size_t)b * CoutTotal + c0 + cl) * HWc + h * WW + w8;
  *(uint4*)ob = pack8(a0);
  *(uint4*)(ob + WW) = pack8(a1);
}

// ---------------- MFMA cov partials + per-channel mu partials ----------------
__global__ __launch_bounds__(TPB) void k_cov4(const bf16_t* __restrict__ qkv,
                                              float* __restrict__ part,
                                              float* __restrict__ mupartC) {
  constexpr int PK = 136;
  __shared__ bf16_t Xt[128 * PK];
  int chunk = blockIdx.x;
  int base = chunk * 128;
  int tid = threadIdx.x, lane = tid & 63, wid = tid >> 6;
  int wm = wid >> 1, wn = wid & 1;
  int cl = lane & 15, rg = lane >> 4;
#pragma unroll
  for (int r = 0; r < 8; ++r) {
    int u = tid + r * TPB;
    int c = u >> 4, l8 = (u & 15) * 8;
    uint4 v0 = *(const uint4*)(&qkv[(size_t)c * HWc + base + l8]);
    uint4 v1 = *(const uint4*)(&qkv[(size_t)C3 * HWc + (size_t)c * HWc + base + l8]);
    unsigned w0[4] = {v0.x, v0.y, v0.z, v0.w};
    unsigned w1[4] = {v1.x, v1.y, v1.z, v1.w};
    float cf[8];
#pragma unroll
    for (int j = 0; j < 8; ++j) {
      float a = b2f((bf16_t)((w0[j >> 1] >> ((j & 1) * 16)) & 0xFFFFu));
      float bq = b2f((bf16_t)((w1[j >> 1] >> ((j & 1) * 16)) & 0xFFFFu));
      cf[j] = 0.5f * (a + bq);
    }
    *(uint4*)(&Xt[c * PK + l8]) = pack8(cf);
  }
  __syncthreads();
  // per-channel mu partials (2 threads/channel)
  {
    int c = tid >> 1, half = tid & 1;
    float s = 0.f;
    for (int l = half * 64; l < half * 64 + 64; ++l)
      s += b2f(Xt[c * PK + l]);
    s += __shfl_xor(s, 1, 64);
    if (half == 0) mupartC[(size_t)chunk * CDIM + c] = s;
  }
  f32x4 acc[4][4];
#pragma unroll
  for (int m = 0; m < 4; ++m)
#pragma unroll
    for (int n = 0; n < 4; ++n) acc[m][n] = (f32x4){0.f, 0.f, 0.f, 0.f};
#pragma unroll
  for (int kk = 0; kk < 4; ++kk) {
    int kof = kk * 32 + rg * 8;
    bf16x8 a[4], bfr[4];
#pragma unroll
    for (int m = 0; m < 4; ++m)
      a[m] = *(const bf16x8*)(&Xt[(wm * 64 + m * 16 + cl) * PK + kof]);
#pragma unroll
    for (int n = 0; n < 4; ++n)
      bfr[n] = *(const bf16x8*)(&Xt[(wn * 64 + n * 16 + cl) * PK + kof]);
#pragma unroll
    for (int m = 0; m < 4; ++m)
#pragma unroll
      for (int n = 0; n < 4; ++n)
        acc[m][n] = __builtin_amdgcn_mfma_f32_16x16x32_bf16(bfr[n], a[m], acc[m][n], 0, 0, 0);
  }
  float* pb = part + (size_t)chunk * CDIM * CDIM;
#pragma unroll
  for (int m = 0; m < 4; ++m) {
    int c = wm * 64 + m * 16 + cl;
#pragma unroll
    for (int n = 0; n < 4; ++n) {
      int d0 = wn * 64 + n * 16 + rg * 4;
      float v[4] = {acc[m][n][0], acc[m][n][1], acc[m][n][2], acc[m][n][3]};
      stv4(&pb[c * CDIM + d0], v);
    }
  }
}

// ---------------- reduce mu partials ----------------
__global__ __launch_bounds__(TPB) void k_muredC(const float* __restrict__ mupartC,
                                                float* __restrict__ mu) {
  int c = blockIdx.x;
  int tid = threadIdx.x;
  __shared__ float red[TPB];
  float s = 0.f;
  for (int u = tid; u < CV; u += TPB) s += mupartC[(size_t)u * CDIM + c];
  red[tid] = s;
  __syncthreads();
  for (int st = TPB / 2; st > 0; st >>= 1) {
    if (tid < st) red[tid] += red[tid + st];
    __syncthreads();
  }
  if (tid == 0) mu[c] = red[0] / HWc;
}

// ---------------- covred stage 1: 8-way slice reduce ----------------
__global__ __launch_bounds__(TPB) void k_covred1(const float* __restrict__ part,
                                                 float* __restrict__ p2) {
  int t = blockIdx.x * TPB + threadIdx.x;
  int yg = blockIdx.y;
  float s = 0.f;
  for (int p = yg * 36; p < (yg + 1) * 36; ++p)
    s += part[(size_t)p * CDIM * CDIM + t];
  p2[(size_t)yg * CDIM * CDIM + t] = s;
}
// ---------------- covred stage 2 ----------------
__global__ __launch_bounds__(TPB) void k_covred2(const float* __restrict__ p2,
                                                 const float* __restrict__ mu,
                                                 float* __restrict__ cov) {
  int t = blockIdx.x * TPB + threadIdx.x;
  if (t >= CDIM * CDIM) return;
  float s = 0.f;
#pragma unroll
  for (int y = 0; y < 8; ++y) s += p2[(size_t)y * CDIM * CDIM + t];
  int c = t >> 7, d = t & 127;
  cov[t] = s - (float)HWc * mu[c] * mu[d];
}

// ---------------- parallel stable rank ----------------
__global__ __launch_bounds__(CDIM) void k_rank(const float* __restrict__ cov,
                                               int* __restrict__ idx) {
  __shared__ float dsd[CDIM], score[CDIM];
  int tid = threadIdx.x;
  dsd[tid] = sqrtf(cov[tid * CDIM + tid]);
  __syncthreads();
  {
    float s = 0.f, di = dsd[tid];
    for (int d = 0; d < CDIM; ++d) s += cov[tid * CDIM + d] / (di * dsd[d]);
    score[tid] = s;
  }
  __syncthreads();
  {
    float my = score[tid];
    int rank = 0;
    for (int d = 0; d < CDIM; ++d)
      rank += (score[d] > my) || (score[d] == my && d < tid);
    idx[rank] = tid;
  }
}

// ---------------- row inverse-norms BY CHANNEL (vectorized) ----------------
__global__ __launch_bounds__(TPB) void k_norms(const bf16_t* __restrict__ qkv,
                                               float* __restrict__ invq,
                                               float* __restrict__ invk) {
  int ch = blockIdx.x, b = blockIdx.y, which = blockIdx.z;
  const bf16_t* row = qkv + ((size_t)b * C3 + which * CDIM + ch) * HWc;
  __shared__ float red[TPB];
  float s = 0.f;
  for (int u = threadIdx.x; u < HWc / 8; u += TPB)
    s += sumsq8(*(const uint4*)(&row[u * 8]));
  red[threadIdx.x] = s;
  __syncthreads();
  for (int st = TPB / 2; st > 0; st >>= 1) {
    if (threadIdx.x < st) red[threadIdx.x] += red[threadIdx.x + st];
    __syncthreads();
  }
  if (threadIdx.x == 0) {
    float n = fmaxf(sqrtf(red[0]), 1e-12f);
    (which ? invk : invq)[b * CDIM + ch] = 1.f / n;
  }
}

// ---------------- QK^T split-L partials (merged groups, dynamic LDS) ----------------
template <int G>
__device__ __forceinline__ void qk2_impl(char* sm, const bf16_t* __restrict__ qkv,
                                         const int* __restrict__ idx, int start,
                                         float* __restrict__ partial, int nl, int b) {
  constexpr int RT = G / 16;
  constexpr int U  = G * CH2 / 8;
  float (*qs)[CH2 + 2] = (float (*)[CH2 + 2])sm;
  float (*ks)[CH2 + 2] = (float (*)[CH2 + 2])(sm + (size_t)G * (CH2 + 2) * 4);
  int* idxg = (int*)(sm + (size_t)2 * G * (CH2 + 2) * 4);
  int tid = threadIdx.x;
  if (tid < G) idxg[tid] = idx[start + tid];
  __syncthreads();
  int l0 = nl * CH2;
  for (int u = tid; u < U; u += TPB) {
    int r = u / (CH2 / 8), c8 = (u % (CH2 / 8)) * 8;
    int ch = idxg[r];
    uint4 vq = *(const uint4*)(&qkv[((size_t)b * C3 + ch) * HWc + l0 + c8]);
    uint4 vk = *(const uint4*)(&qkv[((size_t)b * C3 + CDIM + ch) * HWc + l0 + c8]);
    unsigned wq[4] = {vq.x, vq.y, vq.z, vq.w};
    unsigned wk[4] = {vk.x, vk.y, vk.z, vk.w};
#pragma unroll
    for (int j = 0; j < 8; ++j) {
      qs[r][c8 + j] = b2f((bf16_t)((wq[j >> 1] >> ((j & 1) * 16)) & 0xFFFFu));
      ks[r][c8 + j] = b2f((bf16_t)((wk[j >> 1] >> ((j & 1) * 16)) & 0xFFFFu));
    }
  }
  __syncthreads();
  int ti = tid & 15, tj = tid >> 4;
  float acc[RT][RT];
#pragma unroll
  for (int m = 0; m < RT; ++m)
#pragma unroll
    for (int n = 0; n < RT; ++n) acc[m][n] = 0.f;
#pragma unroll 4
  for (int l = 0; l < CH2; ++l) {
    float qa[RT], kb[RT];
#pragma unroll
    for (int m = 0; m < RT; ++m) qa[m] = qs[ti * RT + m][l];
#pragma unroll
    for (int n = 0; n < RT; ++n) kb[n] = ks[tj * RT + n][l];
#pragma unroll
    for (int m = 0; m < RT; ++m)
#pragma unroll
      for (int n = 0; n < RT; ++n) acc[m][n] += qa[m] * kb[n];
  }
  float* pb = partial + ((size_t)(b * NL2) + nl) * G * G;
#pragma unroll
  for (int m = 0; m < RT; ++m)
#pragma unroll
    for (int n = 0; n < RT; ++n)
      pb[(ti * RT + m) * G + tj * RT + n] = acc[m][n];
}

__global__ __launch_bounds__(TPB) void k_qk2g(const bf16_t* __restrict__ qkv,
                                              const int* __restrict__ idx,
                                              float* __restrict__ qkpart) {
  extern __shared__ char sm[];
  int nl = blockIdx.x, b = blockIdx.y, gi = blockIdx.z;
  if (gi == 0)      qk2_impl<16>(sm, qkv, idx, 0,  qkpart + 0,       nl, b);
  else if (gi == 1) qk2_impl<32>(sm, qkv, idx, 16, qkpart + 147456,  nl, b);
  else if (gi == 2) qk2_impl<32>(sm, qkv, idx, 48, qkpart + 737280,  nl, b);
  else              qk2_impl<48>(sm, qkv, idx, 80, qkpart + 1327104, nl, b);
}

// ---------------- QK partial reduce, stage 1: 8-way over nl ----------------
__global__ __launch_bounds__(TPB) void k_qkred1(const float* __restrict__ qkpart,
                                                float* __restrict__ qkp2) {
  int t = blockIdx.x * TPB + threadIdx.x;   // 0..9215
  int yg = blockIdx.y;                       // 0..7
  int b = t / 4608, e = t - b * 4608;
  int gi = (e < 256) ? 0 : (e < 1280) ? 1 : (e < 2304) ? 2 : 3;
  const int gg4[4]    = {256, 1024, 1024, 2304};
  const int pgoff[4]  = {0, 147456, 737280, 1327104};
  const int aoff4[4]  = {0, 256, 1280, 2304};
  int GGg = gg4[gi];
  int el = e - aoff4[gi];
  const float* pb = qkpart + pgoff[gi] + (size_t)(b * NL2) * GGg + el;
  float s = 0.f;
  for (int nl = yg * 36; nl < (yg + 1) * 36; ++nl) s += pb[(size_t)nl * GGg];
  qkp2[(size_t)yg * (BN_ * 4608) + t] = s;
}

// ---------------- softmax for all groups (sums qkp2 slices inline) ----------------
__global__ __launch_bounds__(TPB) void k_smg(const float* __restrict__ qkp2,
                                             const int* __restrict__ idx,
                                             const float* __restrict__ invq,
                                             const float* __restrict__ invk,
                                             const float* __restrict__ temperature,
                                             float* __restrict__ attS) {
  int b = blockIdx.x, gi = blockIdx.y;
  int G = dGSZ[gi], start = dGST[gi];
  int GG = G * G;
  float* as = attS + b * 4608 + dAOFF[gi];
  float temp = temperature[gi];
  __shared__ float att[2304];
  __shared__ float ivq[48], ivk[48];
  int tid = threadIdx.x;
  if (tid < G) {
    int ch = idx[start + tid];
    ivq[tid] = invq[b * CDIM + ch];
    ivk[tid] = invk[b * CDIM + ch];
  }
  __syncthreads();
  for (int e = tid; e < GG; e += TPB) {
    int base = b * 4608 + dAOFF[gi] + e;
    float s = 0.f;
#pragma unroll
    for (int y = 0; y < 8; ++y) s += qkp2[(size_t)y * (BN_ * 4608) + base];
    int i = e / G, j = e - i * G;
    att[e] = s * temp * ivq[i] * ivk[j];
  }
  __syncthreads();
  if (tid < G) {
    float mx = -3.4e38f;
    for (int j = 0; j < G; ++j) mx = fmaxf(mx, att[tid * G + j]);
    float ssum = 0.f;
    for (int j = 0; j < G; ++j) { float ex = expf(att[tid * G + j] - mx); att[tid * G + j] = ex; ssum += ex; }
    float inv = 1.f / ssum;
    for (int j = 0; j < G; ++j) att[tid * G + j] *= inv;
  }
  __syncthreads();
  for (int e = tid; e < GG; e += TPB) as[e] = att[e];
}

// ---------------- column-parallel group MLP ----------------
__global__ __launch_bounds__(TPB) void k_imlpg(const float* __restrict__ attS,
                                               const float* __restrict__ qv_cache,
                                               const float* __restrict__ cw0, const float* __restrict__ cb0,
                                               const float* __restrict__ gw0, const float* __restrict__ gb0,
                                               const float* __restrict__ cw1, const float* __restrict__ cb1,
                                               const float* __restrict__ gw1, const float* __restrict__ gb1,
                                               const float* __restrict__ cw2, const float* __restrict__ cb2,
                                               const float* __restrict__ gw2, const float* __restrict__ gb2,
                                               const float* __restrict__ cw3, const float* __restrict__ cb3,
                                               const float* __restrict__ gw3, const float* __restrict__ gb3,
                                               float* __restrict__ attF) {
  int b = blockIdx.x, gi = blockIdx.y, tile = blockIdx.z;
  int G = dGSZ[gi];
  int p0 = tile * 16;
  if (p0 >= G) return;
  int GG = G * G;
  const float* cw_w = (gi == 0) ? cw0 : (gi == 1) ? cw1 : (gi == 2) ? cw2 : cw3;
  const float* cw_b = (gi == 0) ? cb0 : (gi == 1) ? cb1 : (gi == 2) ? cb2 : cb3;
  const float* g_w  = (gi == 0) ? gw0 : (gi == 1) ? gw1 : (gi == 2) ? gw2 : gw3;
  const float* g_b  = (gi == 0) ? gb0 : (gi == 1) ? gb1 : (gi == 2) ? gb2 : gb3;
  const float* as = attS + b * 4608 + dAOFF[gi];
  float* af = attF + dABASE[gi] + (size_t)b * GG;
  int tid = threadIdx.x;
  __shared__ float cwW[2 * 48 * 48];
  __shared__ float gW[48 * 48];
  __shared__ float attC[48 * 16], t1C[48 * 16], scC[48 * 16], shC[48 * 16],
                   x1pC[48 * 16], t2C[48 * 16];
  for (int e = tid; e < 2 * G * G; e += TPB) cwW[e] = cw_w[e];
  for (int e = tid; e < G * G; e += TPB) gW[e] = g_w[e];
  for (int u = tid; u < G * 16; u += TPB) {
    int c = u >> 4, pl = u & 15;
    int p = p0 + pl;
    float av = 0.f, pv = 0.f;
    if (p < G) {
      av = as[c * G + p];
      int so = c * CDIM / G, eo = ((c + 1) * CDIM + G - 1) / G;
      int sp = p * CDIM / G, ep = ((p + 1) * CDIM + G - 1) / G;
      float ssum = 0.f;
      for (int i2 = so; i2 < eo; ++i2)
        for (int j2 = sp; j2 < ep; ++j2) ssum += qv_cache[i2 * CDIM + j2];
      pv = ssum / (float)((eo - so) * (ep - sp));
    }
    attC[u] = av;
    t1C[u] = pv + av;
  }
  __syncthreads();
  for (int u = tid; u < 2 * G * 16; u += TPB) {
    int o = u >> 4, pl = u & 15;
    float acc = cw_b[o];
    for (int c = 0; c < G; ++c) acc += cwW[o * G + c] * t1C[c * 16 + pl];
    if (o < G) scC[o * 16 + pl] = acc;
    else       shC[(o - G) * 16 + pl] = acc;
  }
  __syncthreads();
  for (int u = tid; u < G * 16; u += TPB)
    x1pC[u] = attC[u] * scC[u] + shC[u];
  __syncthreads();
  for (int u = tid; u < G * 16; u += TPB) {
    int o = u >> 4, pl = u & 15;
    float acc = g_b[o];
    for (int c = 0; c < G; ++c) acc += gW[o * G + c] * x1pC[c * 16 + pl];
    t2C[u] = acc;
  }
  __syncthreads();
  for (int u = tid; u < G * 16; u += TPB) {
    int c = u >> 4, pl = u & 15;
    int p = p0 + pl;
    if (p < G)
      af[c * G + p] = x1pC[u] * gelu_f(t2C[u]) + attC[u];
  }
}

// ---------------- att @ V (MFMA) + (qn+kn) fused, merged groups ----------------
template <int G, int GP>
__device__ __forceinline__ void av2_impl(char* sm, const bf16_t* __restrict__ qkv,
                                         const int* __restrict__ idx,
                                         const float* __restrict__ attF,
                                         const float* __restrict__ invq,
                                         const float* __restrict__ invk, int start,
                                         bf16_t* __restrict__ out_all,
                                         bf16_t* __restrict__ s_buf, int l0, int b) {
  constexpr int PK = GP + 8;
  constexpr int MT = G / 16;
  bf16_t* Vt = (bf16_t*)sm;                                     // [128][PK]
  bf16_t* Ab = (bf16_t*)(sm + (size_t)128 * PK * 2);            // [G][PK]
  int* idxg  = (int*)(sm + (size_t)128 * PK * 2 + (size_t)G * PK * 2);
  int tid = threadIdx.x, lane = tid & 63, wid = tid >> 6;
  int cl = lane & 15, rg = lane >> 4;
  if (tid < G) idxg[tid] = idx[start + tid];
  __syncthreads();
  for (int u = tid; u < (GP / 2) * 16; u += TPB) {
    int j2 = u % (GP / 2), lb = u / (GP / 2);
    int ja = j2 * 2;
    uint4 rA = {0u,0u,0u,0u}, rB = {0u,0u,0u,0u};
    if (ja < G)     rA = *(const uint4*)(&qkv[((size_t)b * C3 + 2 * CDIM + idxg[ja]) * HWc + l0 + lb * 8]);
    if (ja + 1 < G) rB = *(const uint4*)(&qkv[((size_t)b * C3 + 2 * CDIM + idxg[ja + 1]) * HWc + l0 + lb * 8]);
    unsigned wa[4] = {rA.x, rA.y, rA.z, rA.w};
    unsigned wb[4] = {rB.x, rB.y, rB.z, rB.w};
#pragma unroll
    for (int j = 0; j < 8; ++j) {
      unsigned va = (wa[j >> 1] >> ((j & 1) * 16)) & 0xFFFFu;
      unsigned vb = (wb[j >> 1] >> ((j & 1) * 16)) & 0xFFFFu;
      *(unsigned*)(&Vt[(lb * 8 + j) * PK + ja]) = va | (vb << 16);
    }
  }
  for (int e = tid; e < G * GP; e += TPB) {
    int p = e / GP, j = e - p * GP;
    Ab[p * PK + j] = (j < G) ? f2b(attF[(size_t)b * G * G + p * G + j]) : (bf16_t)0;
  }
  __syncthreads();
  f32x4 acc[MT][2];
#pragma unroll
  for (int m = 0; m < MT; ++m)
#pragma unroll
    for (int n = 0; n < 2; ++n) acc[m][n] = (f32x4){0.f, 0.f, 0.f, 0.f};
#pragma unroll
  for (int kk = 0; kk < GP / 32; ++kk) {
    int kof = kk * 32 + rg * 8;
    bf16x8 a[MT], bfr[2];
#pragma unroll
    for (int m = 0; m < MT; ++m)
      a[m] = *(const bf16x8*)(&Ab[(m * 16 + cl) * PK + kof]);
#pragma unroll
    for (int n = 0; n < 2; ++n)
      bfr[n] = *(const bf16x8*)(&Vt[(wid * 32 + n * 16 + cl) * PK + kof]);
#pragma unroll
    for (int m = 0; m < MT; ++m)
#pragma unroll
      for (int n = 0; n < 2; ++n)
        acc[m][n] = __builtin_amdgcn_mfma_f32_16x16x32_bf16(bfr[n], a[m], acc[m][n], 0, 0, 0);
  }
#pragma unroll
  for (int m = 0; m < MT; ++m) {
    int p = m * 16 + cl;
    int pg = start + p;
    int ch = idxg[p];
    float iq = invq[b * CDIM + ch], ik = invk[b * CDIM + ch];
#pragma unroll
    for (int n = 0; n < 2; ++n) {
      int lg = l0 + wid * 32 + n * 16 + rg * 4;
      float q4[4], k4[4];
      ldv4(&qkv[((size_t)b * C3 + ch) * HWc + lg], q4);
      ldv4(&qkv[((size_t)b * C3 + CDIM + ch) * HWc + lg], k4);
      float vo[4], vs[4];
#pragma unroll
      for (int r = 0; r < 4; ++r) {
        vo[r] = acc[m][n][r];
        vs[r] = vo[r] + q4[r] * iq + k4[r] * ik;
      }
      size_t off = ((size_t)b * CDIM + pg) * HWc + lg;
      stv4(&out_all[off], vo);
      stv4(&s_buf[off], vs);
    }
  }
}

__global__ __launch_bounds__(TPB) void k_avg(const bf16_t* __restrict__ qkv,
                                             const int* __restrict__ idx,
                                             const float* __restrict__ atts,
                                             const float* __restrict__ invq,
                                             const float* __restrict__ invk,
                                             bf16_t* __restrict__ out_all,
                                             bf16_t* __restrict__ s_buf) {
  extern __shared__ char sm[];
  int l0 = blockIdx.x * 128, b = blockIdx.y, gi = blockIdx.z;
  if (gi == 0)      av2_impl<16, 32>(sm, qkv, idx, atts + 0,    invq, invk, 0,  out_all, s_buf, l0, b);
  else if (gi == 1) av2_impl<32, 32>(sm, qkv, idx, atts + 512,  invq, invk, 16, out_all, s_buf, l0, b);
  else if (gi == 2) av2_impl<32, 32>(sm, qkv, idx, atts + 2560, invq, invk, 48, out_all, s_buf, l0, b);
  else              av2_impl<48, 64>(sm, qkv, idx, atts + 4608, invq, invk, 80, out_all, s_buf, l0, b);
}

// ---------------- qv_new: bilinear upsample + floor + EMA ----------------
__global__ __launch_bounds__(TPB) void k_qvnew(const float* __restrict__ attsF,
                                               const float* __restrict__ qv_cache,
                                               float* __restrict__ out_qv) {
  int t = blockIdx.x * TPB + threadIdx.x;
  if (t >= CDIM * CDIM) return;
  int r = t >> 7, cq = t & 127;
  const int gs[4]   = {16, 32, 32, 48};
  const int base[4] = {0, 512, 2560, 4608};
  float acc = 0.f;
  for (int gi = 0; gi < 4; ++gi) {
    int g = gs[gi], gg = g * g;
    const float* a0 = attsF + base[gi];
    float scale = (float)g / CDIM;
    float fr = (r + 0.5f) * scale - 0.5f;
    float fc = (cq + 0.5f) * scale - 0.5f;
    float flr = floorf(fr), flc = floorf(fc);
    int i0 = (int)flr, j0 = (int)flc;
    float wr = fr - flr, wcw = fc - flc;
    int i0c = max(i0, 0), i1c = min(i0 + 1, g - 1);
    int j0c = max(j0, 0), j1c = min(j0 + 1, g - 1);
    float m00 = 0.5f * (a0[i0c * g + j0c] + a0[gg + i0c * g + j0c]);
    float m01 = 0.5f * (a0[i0c * g + j1c] + a0[gg + i0c * g + j1c]);
    float m10 = 0.5f * (a0[i1c * g + j0c] + a0[gg + i1c * g + j0c]);
    float m11 = 0.5f * (a0[i1c * g + j1c] + a0[gg + i1c * g + j1c]);
    float val = (1.f - wr) * ((1.f - wcw) * m00 + wcw * m01)
              + wr * ((1.f - wcw) * m10 + wcw * m11);
    acc += floorf(val);
  }
  out_qv[t] = qv_cache[t] * 0.9f + acc * 0.1f;
}

// ---------------- ffn: dw3 pair + gelu-gate, 2 rows x 8 px per thread ----------------
__global__ __launch_bounds__(TPB) void k_dwgeluv(const bf16_t* __restrict__ y0c,
                                                 const float* __restrict__ wt,
                                                 bf16_t* __restrict__ z,
                                                 int Cc, int c0, long totalG) {
  long t = (long)blockIdx.x * TPB + threadIdx.x;
  if (t >= totalG) return;
  int g = (int)(t % (HWc / 16));
  long bc = t / (HWc / 16);
  int cl = (int)(bc % Cc);
  int b = (int)(bc / Cc);
  int rp = g / (WW / 8), w8 = (g % (WW / 8)) * 8;
  int h = rp * 2;
  const bf16_t* i1 = y0c + ((size_t)b * 2 * Cc + cl) * HWc;
  const bf16_t* i2 = i1 + (size_t)Cc * HWc;
  const float* w1 = wt + (size_t)(c0 + cl) * 9;
  const float* w2 = wt + (size_t)(HID + c0 + cl) * 9;
  float rv[4][10];
#pragma unroll
  for (int dy = 0; dy < 4; ++dy) {
    int hh = h - 1 + dy;
    if (hh < 0 || hh >= HH) {
#pragma unroll
      for (int j = 0; j < 10; ++j) rv[dy][j] = 0.f;
    } else {
      dwrow(i1 + hh * WW + w8, w8, rv[dy]);
    }
  }
  float g0[8], g1[8];
#pragma unroll
  for (int j = 0; j < 8; ++j) {
    float s0 = 0.f, s1 = 0.f;
#pragma unroll
    for (int dy = 0; dy < 3; ++dy)
#pragma unroll
      for (int dx = 0; dx < 3; ++dx) {
        float wv = w1[dy * 3 + dx];
        s0 += rv[dy][j + dx] * wv;
        s1 += rv[dy + 1][j + dx] * wv;
      }
    g0[j] = gelu_f(s0); g1[j] = gelu_f(s1);
  }
#pragma unroll
  for (int dy = 0; dy < 4; ++dy) {
    int hh = h - 1 + dy;
    if (hh < 0 || hh >= HH) {
#pragma unroll
      for (int j = 0; j < 10; ++j) rv[dy][j] = 0.f;
    } else {
      dwrow(i2 + hh * WW + w8, w8, rv[dy]);
    }
  }
  float o0[8], o1[8];
#pragma unroll
  for (int j = 0; j < 8; ++j) {
    float s0 = 0.f, s1 = 0.f;
#pragma unroll
    for (int dy = 0; dy < 3; ++dy)
#pragma unroll
      for (int dx = 0; dx < 3; ++dx) {
        float wv = w2[dy * 3 + dx];
        s0 += rv[dy][j + dx] * wv;
        s1 += rv[dy + 1][j + dx] * wv;
      }
    o0[j] = g0[j] * s0; o1[j] = g1[j] * s1;
  }
  bf16_t* zp = z + ((size_t)b * HID + c0 + cl) * HWc + h * WW + w8;
  *(uint4*)zp = pack8(o0);
  *(uint4*)(zp + WW) = pack8(o1);
}

// ---------------- host ----------------
extern "C" void kernel_launch(void* const* d_in, const int* in_sizes, int n_in,
                              void* d_out, int out_size, void* d_ws, size_t ws_size,
                              hipStream_t stream) {
  if (ws_size < WS_NEED) return;  // workspace insufficient

  const float* x        = (const float*)d_in[0];
  const float* qv_cache = (const float*)d_in[1];
  const float* ln1_w    = (const float*)d_in[2];
  const float* ln1_b    = (const float*)d_in[3];
  const float* ln2_w    = (const float*)d_in[4];
  const float* ln2_b    = (const float*)d_in[5];
  const float* temperature = (const float*)d_in[6];
  const float* w_qkv    = (const float*)d_in[7];
  const float* w_qkv_dw = (const float*)d_in[8];
  const float* w_proj   = (const float*)d_in[9];
  const float* intra_down_w = (const float*)d_in[10];
  const float* intra_down_b = (const float*)d_in[11];
  const float* intra_up_w   = (const float*)d_in[12];
  const float* intra_up_b   = (const float*)d_in[13];
  const float* intra_gate_w = (const float*)d_in[14];
  const float* intra_gate_b = (const float*)d_in[15];
  const float* ffn_in_w  = (const float*)d_in[32];
  const float* ffn_dw_w  = (const float*)d_in[33];
  const float* ffn_out_w = (const float*)d_in[34];

  char* wsb = (char*)d_ws;
  float* out    = (float*)d_out;
  float* out_qv = out + (size_t)BN_ * CDIM * HWc;
  bf16_t* xn2   = (bf16_t*)d_out;

  float*  attS    = (float*)(wsb + oATTS2);
  bf16_t* wb      = (bf16_t*)(wsb + oWB);
  float*  qkp2    = (float*)(wsb + oQKP2);
  float*  mupartC = (float*)(wsb + oMUPC);
  float*  atts    = (float*)(wsb + oATTS);
  float*  invqA   = (float*)(wsb + oNORMQ);
  float*  invkA   = (float*)(wsb + oNORMK);
  int*    idx     = (int*)(wsb + oIDX);
  float*  mu      = (float*)(wsb + oMU);
  float*  cov     = (float*)(wsb + oCOV);
  bf16_t* qkv     = (bf16_t*)(wsb + oQKV);
  bf16_t* xn      = (bf16_t*)(wsb + oXN);
  bf16_t* out_all = (bf16_t*)(wsb + oOUTALL);
  bf16_t* sbuf    = (bf16_t*)(wsb + oSBUF);
  bf16_t* chunk1  = (bf16_t*)(wsb + oCHUNK1);
  float*  covpart = (float*)(wsb + oCOVPART);
  float*  covp2   = (float*)(wsb + oCOVP2);
  float*  qkpart  = (float*)(wsb + oQKPART);
  bf16_t* gated   = (bf16_t*)(wsb + oGATED);
  bf16_t* dbuf    = (bf16_t*)(wsb + oDBUF);
  bf16_t* x1b     = (bf16_t*)(wsb + oX1B);
  bf16_t* y0c     = (bf16_t*)(wsb + oY0C);
  bf16_t* zbuf    = (bf16_t*)(wsb + oZ);

  const bf16_t* wq_b   = wb + eWQ;
  const bf16_t* gate_b = wb + eGATE;
  const bf16_t* down_b = wb + eDOWN;
  const bf16_t* up_b   = wb + eUP;
  const bf16_t* proj_b = wb + ePROJ;
  const bf16_t* ffi_b  = wb + eFFI;
  const bf16_t* ffo_b  = wb + eFFO;

  const int GX = HWc / 128;
  const int NOS = 1 << 30;
  dim3 gA(GX, BN_);

  // 0. pre-convert weights fp32->bf16
  k_wcvt<<<(eTOT + TPB - 1) / TPB, TPB, 0, stream>>>(
      w_qkv, intra_gate_w, intra_down_w, intra_up_w, w_proj, ffn_in_w, ffn_out_w, wb);

  // 1. LN1: xn = LN(x)
  k_ln<float><<<(BN_ * HWc + TPB - 1) / TPB, TPB, 0, stream>>>(x, ln1_w, ln1_b, xn);

  // 2+3. qkv = dw3(c1x1(xn, w_qkv)) in 2 chunks of 192 channels
  for (int ci = 0; ci < 2; ++ci) {
    int c0 = ci * 192;
    k_mgA<bf16_t, float, 128, 0><<<gA, TPB, 0, stream>>>(
        wq_b + (size_t)c0 * CDIM, wq_b, NOS, nullptr, xn, nullptr, chunk1,
        192, CDIM, 192, 0);
    long totG = (long)BN_ * 192 * (HWc / 16);
    k_dw3v<<<(unsigned)((totG + TPB - 1) / TPB), TPB, 0, stream>>>(
        chunk1, w_qkv_dw, qkv, 192, c0, C3, totG);
  }

  // 4. inverse norms by channel (no idx dependency)
  k_norms<<<dim3(CDIM, BN_, 2), TPB, 0, stream>>>(qkv, invqA, invkA);

  // 5-7. correlation sort (cov + mu in one pass)
  k_cov4<<<CV, TPB, 0, stream>>>(qkv, covpart, mupartC);
  k_muredC<<<CDIM, TPB, 0, stream>>>(mupartC, mu);
  k_covred1<<<dim3(64, 8), TPB, 0, stream>>>(covpart, covp2);
  k_covred2<<<64, TPB, 0, stream>>>(covp2, mu, cov);
  k_rank<<<1, CDIM, 0, stream>>>(cov, idx);

  // 9. QK^T partials for all 4 groups in ONE dispatch
  {
    size_t dyn = (size_t)2 * 48 * (CH2 + 2) * 4 + 48 * 4;
    k_qk2g<<<dim3(NL2, BN_, 4), TPB, dyn, stream>>>(qkv, idx, qkpart);
  }
  // 10. reduce stage 1 -> qkp2 (stage 2 folded into softmax)
  k_qkred1<<<dim3(36, 8), TPB, 0, stream>>>(qkpart, qkp2);
  // 11. softmax (sums qkp2 inline) -> attS
  k_smg<<<dim3(BN_, 4), TPB, 0, stream>>>(qkp2, idx, invqA, invkA, temperature, attS);
  // 12. column-parallel group MLP -> attF
  k_imlpg<<<dim3(BN_, 4, 3), TPB, 0, stream>>>(
      attS, qv_cache,
      (const float*)d_in[16], (const float*)d_in[17], (const float*)d_in[18], (const float*)d_in[19],
      (const float*)d_in[20], (const float*)d_in[21], (const float*)d_in[22], (const float*)d_in[23],
      (const float*)d_in[24], (const float*)d_in[25], (const float*)d_in[26], (const float*)d_in[27],
      (const float*)d_in[28], (const float*)d_in[29], (const float*)d_in[30], (const float*)d_in[31],
      atts);
  // 13. att@V (MFMA) + s
  {
    size_t dyn = (size_t)128 * 72 * 2 + (size_t)48 * 72 * 2 + 48 * 4;
    k_avg<<<dim3(HWc / 128, BN_, 4), TPB, dyn, stream>>>(
        qkv, idx, atts, invqA, invkA, out_all, sbuf);
  }
  // qv_new
  k_qvnew<<<(CDIM * CDIM + TPB - 1) / TPB, TPB, 0, stream>>>(atts, qv_cache, out_qv);

  // gated channel-MLP (qkv dead from here); gate multiplier read from LDS (EPI=3)
  k_mgA<bf16_t, float, 128, 3><<<gA, TPB, 0, stream>>>(
      gate_b, gate_b, NOS, intra_gate_b, sbuf, nullptr, gated,
      CDIM, CDIM, CDIM, 0);
  k_mgA<bf16_t, float, 128, 0><<<gA, TPB, 0, stream>>>(
      down_b, down_b, NOS, intra_down_b, gated, nullptr, dbuf,
      CDIM / 2, CDIM, CDIM / 2, 0);
  k_mgA<bf16_t, bf16_t, 64, 1><<<gA, TPB, 0, stream>>>(
      up_b, up_b, NOS, intra_up_b, dbuf, out_all, out_all,
      CDIM, CDIM / 2, CDIM, CDIM);
  // x1b = bf16(x + proj(out_all))
  k_mgA<bf16_t, float, 128, 1><<<gA, TPB, 0, stream>>>(
      proj_b, proj_b, NOS, nullptr, out_all, x, x1b, CDIM, CDIM, CDIM, CDIM);
  // LN2: xn2 = LN(x1b)
  k_ln<bf16_t><<<(BN_ * HWc + TPB - 1) / TPB, TPB, 0, stream>>>(x1b, ln2_w, ln2_b, xn2);

  // FFN in 3 chunks (y0c <= 33.6 MB in outall span; z full in qkv span)
  const int fcc[3] = {114, 114, 112};
  const int fc0[3] = {0, 114, 228};
  for (int ci = 0; ci < 3; ++ci) {
    int Cc = fcc[ci], c0 = fc0[ci];
    k_mgA<bf16_t, float, 128, 0><<<gA, TPB, 0, stream>>>(
        ffi_b + (size_t)c0 * CDIM, ffi_b + (size_t)(HID + c0) * CDIM, Cc,
        nullptr, xn2, nullptr, y0c, 2 * Cc, CDIM, 2 * Cc, 0);
    long totG = (long)BN_ * Cc * (HWc / 16);
    k_dwgeluv<<<(unsigned)((totG + TPB - 1) / TPB), TPB, 0, stream>>>(
        y0c, ffn_dw_w, zbuf, Cc, c0, totG);
  }
  // out = x1b + c1x1(z, ffn_out_w)
  k_mgB<float, bf16_t, 1><<<gA, TPB, 0, stream>>>(
      ffo_b, nullptr, zbuf, x1b, out, CDIM, HID, HID, CDIM, CDIM);
}